// Round 9
// baseline (134.287 us; speedup 1.0000x reference)
//
#include <hip/hip_runtime.h>

#define B_  32
#define C_  128
#define CS  64
#define H_  64
#define W_  64
#define HW  (H_*W_)

typedef __attribute__((ext_vector_type(8))) short bf16x8_t;
typedef __attribute__((ext_vector_type(4))) float f32x4_t;
typedef unsigned short u16;
typedef unsigned int   u32;

__device__ __forceinline__ float silu_f(float v) { return v / (1.f + __expf(-v)); }

__device__ __forceinline__ u16 f2bf(float f) {
    u32 u = __float_as_uint(f);
    u = (u + 0x7FFFu + ((u >> 16) & 1u)) >> 16;   // RNE
    return (u16)u;
}
__device__ __forceinline__ float bf2f(u16 u) {
    return __uint_as_float(((u32)u) << 16);
}
__device__ __forceinline__ u32 pack2(float a, float b) {
    return (u32)f2bf(a) | ((u32)f2bf(b) << 16);
}

__device__ __forceinline__ void get_coeffs(const float* __restrict__ wts,
                                           const int* __restrict__ idxs, int b,
                                           float& c0, float& c1, float& c2, float& cid) {
    int   i0 = idxs[b*2+0], i1 = idxs[b*2+1];
    float w0 = wts[b*2+0],  w1 = wts[b*2+1];
    c0  = (i0==0?w0:0.f)   + (i1==0?w1:0.f);
    c1  = (i0==1?w0:0.f)   + (i1==1?w1:0.f);
    c2  = (i0==2?w0:0.f)   + (i1==2?w1:0.f);
    cid = (i0==3?0.1f:0.f) + (i1==3?0.1f:0.f);
}

// ---- weight prep: MFMA-fragment-ordered bf16 weights --------------------------
// Wt0f: e0  [tap9][kc2][cog8][lane64][8]   A[row=co=cog*16+(l&15)][k=kc*32+(l>>4)*8+j]
// Wt2f: e2a [tap9][kc4][cog4][lane64][8]
// Wt1f: e1pw[kc2][cog8][lane64][8]
__global__ __launch_bounds__(256) void k_prep(
    const float* __restrict__ e0w, const float* __restrict__ e2aw, const float* __restrict__ e1pw,
    u16* __restrict__ Wt0f, u16* __restrict__ Wt2f, u16* __restrict__ Wt1f)
{
    const int i0 = blockIdx.x*256 + threadIdx.x, stride = gridDim.x*256;
    for (int i = i0; i < 73728; i += stride) {
        int j = i&7, lane = (i>>3)&63, cog = (i>>9)&7, kc = (i>>12)&1, tap = i>>13;
        int co = cog*16 + (lane&15), ci = kc*32 + (lane>>4)*8 + j;
        Wt0f[i] = f2bf(e0w[(size_t)(co*64 + ci)*9 + tap]);
    }
    for (int i = i0; i < 73728; i += stride) {
        int j = i&7, lane = (i>>3)&63, cog = (i>>9)&3, kc = (i>>11)&3, tap = i>>13;
        int co = cog*16 + (lane&15), ci = kc*32 + (lane>>4)*8 + j;
        Wt2f[i] = f2bf(e2aw[(size_t)(co*128 + ci)*9 + tap]);
    }
    for (int i = i0; i < 8192; i += stride) {
        int j = i&7, lane = (i>>3)&63, cog = (i>>9)&7, kc = (i>>12)&1;
        int co = cog*16 + (lane&15), ci = kc*32 + (lane>>4)*8 + j;
        Wt1f[i] = f2bf(e1pw[(size_t)co*64 + ci]);
    }
}

// ---- NCHW fp32 -> two padded NHWC bf16 planes [b][66][66][64], zero borders ----
__global__ __launch_bounds__(256) void k_to_nhwc(
    const float* __restrict__ x, const float* __restrict__ wts, const int* __restrict__ idxs,
    u16* __restrict__ xhA, u16* __restrict__ xhB)
{
    const int b = blockIdx.y, h = blockIdx.x, t = threadIdx.x;
    float c0, c1, c2, cid;
    get_coeffs(wts, idxs, b, c0, c1, c2, cid);
    if (c0 == 0.f && c2 == 0.f) return;
    const int np = (c2 != 0.f) ? 2 : 1;
    const int chmax = np*64;

    __shared__ float ld[128*66];
    for (int i = t; i < chmax*16; i += 256) {
        int ch = i >> 4, q = i & 15;
        float4 v = *(const float4*)(x + ((size_t)(b*C_+ch))*HW + h*64 + q*4);
        float* p = &ld[ch*66 + q*4];
        p[0] = v.x; p[1] = v.y; p[2] = v.z; p[3] = v.w;
    }
    __syncthreads();

    const int px = t >> 2, sub = t & 3;
    const size_t base64 = ((size_t)(b*66 + h+1)*66 + (px+1))*64;
    for (int c = sub; c < chmax/8; c += 4) {
        uint4 v;
        u32 w[4];
        #pragma unroll
        for (int k = 0; k < 4; ++k)
            w[k] = pack2(ld[(c*8 + 2*k)*66 + px], ld[(c*8 + 2*k + 1)*66 + px]);
        v.x = w[0]; v.y = w[1]; v.z = w[2]; v.w = w[3];
        u16* dst = (c < 8) ? (xhA + base64 + c*8) : (xhB + base64 + (c-8)*8);
        *(uint4*)dst = v;
    }
    // zero border cols 0 and 65 of this row
    for (int i = t; i < 16*np; i += 256) {
        int pl = i >> 4, j = i & 15;
        int col = (j >> 3)*65, cg = j & 7;
        u16* ph = pl ? xhB : xhA;
        uint4 z; z.x = z.y = z.z = z.w = 0u;
        *(uint4*)(ph + ((size_t)(b*66 + h+1)*66 + col)*64 + cg*8) = z;
    }
    // zero border rows 0 / 65
    if (h == 0 || h == 63) {
        int r = (h == 0) ? 0 : 65;
        for (int i = t; i < 66*8*np; i += 256) {
            int pl = i / (66*8), j = i % (66*8);
            int col = j >> 3, cg = j & 7;
            u16* ph = pl ? xhB : xhA;
            uint4 z; z.x = z.y = z.z = z.w = 0u;
            *(uint4*)(ph + ((size_t)(b*66 + r)*66 + (size_t)col)*64 + cg*8) = z;
        }
    }
}

// ---- per-wave conv: NCF couts x NPF*16 px over K=KCT*32, LDS B, prefetch A ----
// NPF==8: pf covers 2 rows x 64 cols (prow=pf>>2). NPF==4: one row (=rbase).
// MODE 0 -> out = cexp*silu(bn) + cid*x ; MODE 1 -> g1 = silu(bn) bf16
template<int NCF, int NPF, int KCT, int COUT, int MODE>
__device__ __forceinline__ void conv_wave(
    const char* lin, const u16* __restrict__ Wtf,
    const float* __restrict__ gg, const float* __restrict__ bbn,
    const float* __restrict__ mm, const float* __restrict__ vv,
    const float* __restrict__ x, float* __restrict__ out, u16* __restrict__ g1,
    int b, int orow0, int rbase, int cobase, int lane, float cexp, float cid)
{
    constexpr int NIT = 9*KCT;
    const int l15 = lane & 15, kg = lane >> 4;

    f32x4_t acc[NCF][NPF];
    #pragma unroll
    for (int cf = 0; cf < NCF; ++cf)
        #pragma unroll
        for (int pf = 0; pf < NPF; ++pf)
            acc[cf][pf] = (f32x4_t){0.f, 0.f, 0.f, 0.f};

    const u16* wb = Wtf + (size_t)(cobase >> 4)*512 + (size_t)lane*8;

    bf16x8_t aC[NCF], aN[NCF];
    auto loadA = [&](int it, bf16x8_t* a) {
        const u16* wt = wb + (size_t)(it*(COUT/16))*512;
        #pragma unroll
        for (int cf = 0; cf < NCF; ++cf)
            a[cf] = *(const bf16x8_t*)(wt + (cf << 9));
    };
    auto ldsB = [&](int it, int pf) -> bf16x8_t {
        const int tap = it / KCT, kcg = it % KCT;
        const int pl = kcg >> 1, kc = kcg & 1;
        const int dh = tap / 3, dwp = tap % 3;
        const int prow = (NPF == 8) ? (pf >> 2) : rbase;
        const int pcol = (NPF == 8) ? ((pf & 3)*16) : (pf*16);
        const int p = (prow + dh)*66 + pcol + l15 + dwp;
        u32 a = (u32)p*128 + (u32)kc*64 + (u32)kg*16;
        a ^= ((u32)(p & 7)) << 4;
        return *(const bf16x8_t*)(lin + pl*33792 + a);
    };

    loadA(0, aC);
    #pragma unroll
    for (int it = 0; it < NIT; ++it) {
        bf16x8_t* ac = (it & 1) ? aN : aC;
        bf16x8_t* an = (it & 1) ? aC : aN;
        if (it + 1 < NIT) loadA(it + 1, an);
        #pragma unroll
        for (int pf = 0; pf < NPF; ++pf) {
            bf16x8_t bfr = ldsB(it, pf);
            #pragma unroll
            for (int cf = 0; cf < NCF; ++cf)
                acc[cf][pf] = __builtin_amdgcn_mfma_f32_16x16x32_bf16(ac[cf], bfr, acc[cf][pf], 0, 0, 0);
        }
    }

    // D: col=lane&15=pixel, row=(lane>>4)*4+reg=cout
    #pragma unroll
    for (int cf = 0; cf < NCF; ++cf) {
        float sarr[4], tarr[4];
        #pragma unroll
        for (int r = 0; r < 4; ++r) {
            int co = cobase + cf*16 + kg*4 + r;
            float s = gg[co] * rsqrtf(vv[co] + 1e-5f);
            sarr[r] = s; tarr[r] = bbn[co] - mm[co]*s;
        }
        #pragma unroll
        for (int pf = 0; pf < NPF; ++pf) {
            const int prow = (NPF == 8) ? (pf >> 2) : rbase;
            const int pcol = (NPF == 8) ? ((pf & 3)*16) : (pf*16);
            size_t rowoff = (size_t)(orow0 + prow)*64 + pcol + l15;
            #pragma unroll
            for (int r = 0; r < 4; ++r) {
                int co = cobase + cf*16 + kg*4 + r;
                float v = silu_f(acc[cf][pf][r]*sarr[r] + tarr[r]);
                if (MODE == 0) {
                    size_t o = ((size_t)(b*C_+co))*HW + rowoff;
                    float idv = (cid != 0.f) ? cid*x[o] : 0.f;
                    out[o] = cexp*v + idv;
                } else {
                    g1[((size_t)(b*CS+co))*HW + rowoff] = f2bf(v);
                }
            }
        }
    }
}

// ---- merged conv kernel: 4 waves = {e0 half, e0 half, e2a row, e2a row} -------
// grid (32 bands, B). LDS: both planes of 4 padded rows (67.6 KB).
__global__ __launch_bounds__(256, 2) void k_conv(
    const u16* __restrict__ xhA, const u16* __restrict__ xhB, const float* __restrict__ x,
    const float* __restrict__ wts, const int* __restrict__ idxs,
    const u16* __restrict__ Wt0f, const u16* __restrict__ Wt2f,
    const float* __restrict__ e0g, const float* __restrict__ e0b,
    const float* __restrict__ e0m, const float* __restrict__ e0v,
    const float* __restrict__ e2ag, const float* __restrict__ e2ab,
    const float* __restrict__ e2am, const float* __restrict__ e2av,
    float* __restrict__ out, u16* __restrict__ g1)
{
    __shared__ char lin[2*33792];
    const int b = blockIdx.y, orow0 = blockIdx.x*2, t = threadIdx.x;
    float c0, c1, c2, cid;
    get_coeffs(wts, idxs, b, c0, c1, c2, cid);
    const bool need0 = (c0 != 0.f), need2 = (c2 != 0.f);

    if (!need0 && !need2) {   // identity-only init of these 2 rows (all 128 ch)
        for (int i = t; i < 4096; i += 256) {
            int ch = i >> 5, q = i & 31;
            size_t o = ((size_t)(b*C_+ch))*HW + (size_t)orow0*64 + q*4;
            float4 ov;
            if (cid != 0.f) {
                float4 xv = *(const float4*)(x + o);
                ov.x = cid*xv.x; ov.y = cid*xv.y; ov.z = cid*xv.z; ov.w = cid*xv.w;
            } else { ov.x = ov.y = ov.z = ov.w = 0.f; }
            *(float4*)(out + o) = ov;
        }
        return;
    }

    // stage plane A (+B if e2a active): linear dest, inverse-swizzled source
    {
        const size_t src0 = ((size_t)(b*66 + orow0))*66*64;
        for (int d = t*16; d < 33792; d += 4096) {
            u32 s = (u32)d ^ ((((u32)d >> 7) & 7u) << 4);
            *(uint4*)(lin + d) = *(const uint4*)((const char*)(xhA + src0) + s);
        }
        if (need2) {
            for (int d = t*16; d < 33792; d += 4096) {
                u32 s = (u32)d ^ ((((u32)d >> 7) & 7u) << 4);
                *(uint4*)(lin + 33792 + d) = *(const uint4*)((const char*)(xhB + src0) + s);
            }
        }
    }
    __syncthreads();

    const int wv = t >> 6, lane = t & 63;
    if (wv < 2) {
        if (need0) {
            conv_wave<4, 8, 2, 128, 0>(lin, Wt0f, e0g, e0b, e0m, e0v, x, out, nullptr,
                                       b, orow0, 0, wv*64, lane, c0, cid);
        } else {
            // identity init: this wave covers ch wv*64..+63, 2 rows
            for (int k = 0; k < 32; ++k) {
                int idx = k*64 + lane;
                int ch = wv*64 + (idx >> 5), q = idx & 31;
                size_t o = ((size_t)(b*C_+ch))*HW + (size_t)orow0*64 + q*4;
                float4 ov;
                if (cid != 0.f) {
                    float4 xv = *(const float4*)(x + o);
                    ov.x = cid*xv.x; ov.y = cid*xv.y; ov.z = cid*xv.z; ov.w = cid*xv.w;
                } else { ov.x = ov.y = ov.z = ov.w = 0.f; }
                *(float4*)(out + o) = ov;
            }
        }
    } else {
        if (need2)
            conv_wave<4, 4, 4, 64, 1>(lin, Wt2f, e2ag, e2ab, e2am, e2av, x, nullptr, g1,
                                      b, orow0, wv - 2, 0, lane, c2, 0.f);
    }
}

// ---- fused e1: dw5x5(x_ir) in LDS -> pw1x1 MFMA -> BN/SiLU -> out += c1*e1 ----
__global__ __launch_bounds__(256) void k_e1(
    const float* __restrict__ x, const float* __restrict__ wts, const int* __restrict__ idxs,
    const float* __restrict__ dww, const u16* __restrict__ Wt1f,
    const float* __restrict__ gg, const float* __restrict__ bb,
    const float* __restrict__ mm, const float* __restrict__ vv,
    float* __restrict__ out)
{
    const int b = blockIdx.y, band = blockIdx.x, t = threadIdx.x;
    const int orow0 = band*2;

    float c0, c1, c2, cid;
    get_coeffs(wts, idxs, b, c0, c1, c2, cid);
    if (c1 == 0.f) return;

    __shared__ u16  lin[6*64*70];   // [row6][ch64][col70] cols -2..65 (+pad), bf16
    __shared__ u16  lout[128*72];   // [px128][ci72pad] bf16
    __shared__ float wl[64*26];

    for (int i = t; i < 64*25; i += 256) wl[(i/25)*26 + (i%25)] = dww[i];
    for (int i = t; i < 6*64*16; i += 256) {
        int q = i & 15, ch = (i >> 4) & 63, r = i >> 10;
        int hh = orow0 - 2 + r;
        u32 w0 = 0u, w1 = 0u;
        if (hh >= 0 && hh < H_) {
            float4 v = *(const float4*)(x + ((size_t)(b*C_ + CS + ch))*HW + hh*64 + q*4);
            w0 = pack2(v.x, v.y); w1 = pack2(v.z, v.w);
        }
        u32* dst = (u32*)&lin[(r*64 + ch)*70 + 2 + q*4];
        dst[0] = w0; dst[1] = w1;
    }
    for (int i = t; i < 6*64; i += 256) {
        int ch = i & 63, r = i >> 6;
        *(u32*)&lin[(r*64 + ch)*70]      = 0u;
        u32* e = (u32*)&lin[(r*64 + ch)*70 + 66];
        e[0] = 0u; e[1] = 0u;
    }
    __syncthreads();

    const int lane = t & 63, chl = lane & 15, cs = lane >> 4;
    const int wv = t >> 6, outrow = wv & 1, chhalf = wv >> 1;

    #pragma unroll
    for (int chi = 0; chi < 2; ++chi) {
        const int ch = chhalf*32 + chl + chi*16;
        const float* wch = &wl[ch*26];
        float accp[16];
        #pragma unroll
        for (int p = 0; p < 16; ++p) accp[p] = 0.f;
        #pragma unroll
        for (int kh = 0; kh < 5; ++kh) {
            const u16* src = &lin[((outrow + kh)*64 + ch)*70 + cs*16];
            float rb[20];
            #pragma unroll
            for (int k = 0; k < 10; ++k) {
                u32 u = *(const u32*)(src + 2*k);
                rb[2*k]   = __uint_as_float(u << 16);
                rb[2*k+1] = __uint_as_float(u & 0xFFFF0000u);
            }
            #pragma unroll
            for (int kw = 0; kw < 5; ++kw) {
                float wvv = wch[kh*5 + kw];
                #pragma unroll
                for (int p = 0; p < 16; ++p) accp[p] += rb[p+kw]*wvv;
            }
        }
        const int px0 = outrow*64 + cs*16;
        #pragma unroll
        for (int p = 0; p < 16; ++p) lout[(px0+p)*72 + ch] = f2bf(accp[p]);
    }
    __syncthreads();

    const int l15 = lane & 15, kg = lane >> 4;
    const int cw = wv >> 1, pwv = wv & 1;
    f32x4_t acc[4][4];
    #pragma unroll
    for (int cf = 0; cf < 4; ++cf)
        #pragma unroll
        for (int pf = 0; pf < 4; ++pf)
            acc[cf][pf] = (f32x4_t){0.f, 0.f, 0.f, 0.f};

    #pragma unroll
    for (int kc = 0; kc < 2; ++kc) {
        const u16* wt = Wt1f + (((size_t)(kc*8 + cw*4)) << 9) + lane*8;
        bf16x8_t af[4];
        #pragma unroll
        for (int cf = 0; cf < 4; ++cf) af[cf] = *(const bf16x8_t*)(wt + (cf << 9));
        const int k0 = kc*32 + kg*8;
        #pragma unroll
        for (int pf = 0; pf < 4; ++pf) {
            bf16x8_t bfr = *(const bf16x8_t*)&lout[(pwv*64 + pf*16 + l15)*72 + k0];
            #pragma unroll
            for (int cf = 0; cf < 4; ++cf)
                acc[cf][pf] = __builtin_amdgcn_mfma_f32_16x16x32_bf16(af[cf], bfr, acc[cf][pf], 0, 0, 0);
        }
    }

    #pragma unroll
    for (int cf = 0; cf < 4; ++cf) {
        float sarr[4], tarr[4];
        #pragma unroll
        for (int r = 0; r < 4; ++r) {
            int co = cw*64 + cf*16 + kg*4 + r;
            float s = gg[co] * rsqrtf(vv[co] + 1e-5f);
            sarr[r] = s; tarr[r] = bb[co] - mm[co]*s;
        }
        #pragma unroll
        for (int pf = 0; pf < 4; ++pf) {
            int px = pwv*64 + pf*16 + l15;
            size_t rowoff = (size_t)(orow0 + (px>>6))*64 + (px&63);
            #pragma unroll
            for (int r = 0; r < 4; ++r) {
                int co = cw*64 + cf*16 + kg*4 + r;
                float v = silu_f(acc[cf][pf][r]*sarr[r] + tarr[r]);
                out[((size_t)(b*C_+co))*HW + rowoff] += c1*v;
            }
        }
    }
}

// ---- e2b: out[:, :64] += c2*g1 ; out[:, 64:] += c2*silu(bn(dw5x5(g1))) --------
__global__ __launch_bounds__(256) void k_e2b(
    const u16* __restrict__ g1, const float* __restrict__ wts, const int* __restrict__ idxs,
    const float* __restrict__ dww, const float* __restrict__ gg, const float* __restrict__ bb,
    const float* __restrict__ mm, const float* __restrict__ vv, float* __restrict__ out)
{
    const int b = blockIdx.y, band = blockIdx.x, t = threadIdx.x;
    const int orow0 = band*2;

    float c0, c1, c2, cid;
    get_coeffs(wts, idxs, b, c0, c1, c2, cid);
    if (c2 == 0.f) return;

    __shared__ u16  lin[6*64*70];
    __shared__ float wl[64*26];

    for (int i = t; i < 64*25; i += 256) wl[(i/25)*26 + (i%25)] = dww[i];
    for (int i = t; i < 6*64*16; i += 256) {
        int q = i & 15, ch = (i >> 4) & 63, r = i >> 10;
        int hh = orow0 - 2 + r;
        u32 w0 = 0u, w1 = 0u;
        if (hh >= 0 && hh < H_) {
            const u32* src = (const u32*)(g1 + ((size_t)(b*CS+ch))*HW + hh*64 + q*4);
            w0 = src[0]; w1 = src[1];
        }
        u32* dst = (u32*)&lin[(r*64 + ch)*70 + 2 + q*4];
        dst[0] = w0; dst[1] = w1;
    }
    for (int i = t; i < 6*64; i += 256) {
        int ch = i & 63, r = i >> 6;
        *(u32*)&lin[(r*64 + ch)*70] = 0u;
        u32* e = (u32*)&lin[(r*64 + ch)*70 + 66];
        e[0] = 0u; e[1] = 0u;
    }
    __syncthreads();

    // out[:, :64] += c2*g1 for the 2 center rows (lin rows 2,3)
    for (int i = t; i < 2*64*16; i += 256) {
        int q = i & 15, ch = (i >> 4) & 63, r = i >> 10;
        const u16* src = &lin[((r+2)*64 + ch)*70 + 2 + q*4];
        float* op = out + ((size_t)(b*C_+ch))*HW + (size_t)(orow0+r)*64 + q*4;
        float4 ov = *(float4*)op;
        ov.x += c2*bf2f(src[0]); ov.y += c2*bf2f(src[1]);
        ov.z += c2*bf2f(src[2]); ov.w += c2*bf2f(src[3]);
        *(float4*)op = ov;
    }

    const int lane = t & 63, chl = lane & 15, cs = lane >> 4;
    const int wv = t >> 6, outrow = wv & 1, chhalf = wv >> 1;

    #pragma unroll
    for (int chi = 0; chi < 2; ++chi) {
        const int ch = chhalf*32 + chl + chi*16;
        const float* wch = &wl[ch*26];
        float accp[16];
        #pragma unroll
        for (int p = 0; p < 16; ++p) accp[p] = 0.f;
        #pragma unroll
        for (int kh = 0; kh < 5; ++kh) {
            const u16* src = &lin[((outrow + kh)*64 + ch)*70 + cs*16];
            float rb[20];
            #pragma unroll
            for (int k = 0; k < 10; ++k) {
                u32 u = *(const u32*)(src + 2*k);
                rb[2*k]   = __uint_as_float(u << 16);
                rb[2*k+1] = __uint_as_float(u & 0xFFFF0000u);
            }
            #pragma unroll
            for (int kw = 0; kw < 5; ++kw) {
                float wvv = wch[kh*5 + kw];
                #pragma unroll
                for (int p = 0; p < 16; ++p) accp[p] += rb[p+kw]*wvv;
            }
        }
        float s = gg[ch] * rsqrtf(vv[ch] + 1e-5f);
        float tt = bb[ch] - mm[ch]*s;
        float* op = out + ((size_t)(b*C_ + CS + ch))*HW + (size_t)(orow0+outrow)*64 + cs*16;
        #pragma unroll
        for (int q = 0; q < 4; ++q) {
            float4 ov = *(float4*)(op + q*4);
            ov.x += c2*silu_f(accp[q*4+0]*s + tt);
            ov.y += c2*silu_f(accp[q*4+1]*s + tt);
            ov.z += c2*silu_f(accp[q*4+2]*s + tt);
            ov.w += c2*silu_f(accp[q*4+3]*s + tt);
            *(float4*)(op + q*4) = ov;
        }
    }
}

extern "C" void kernel_launch(void* const* d_in, const int* in_sizes, int n_in,
                              void* d_out, int out_size, void* d_ws, size_t ws_size,
                              hipStream_t stream) {
    const float* x    = (const float*)d_in[0];
    const float* wts  = (const float*)d_in[1];
    const int*   idxs = (const int*)  d_in[2];
    const float* e0w  = (const float*)d_in[3];
    const float* e0g  = (const float*)d_in[4];
    const float* e0b  = (const float*)d_in[5];
    const float* e0m  = (const float*)d_in[6];
    const float* e0v  = (const float*)d_in[7];
    const float* e1dw = (const float*)d_in[8];
    const float* e1pw = (const float*)d_in[9];
    const float* e1g  = (const float*)d_in[10];
    const float* e1b  = (const float*)d_in[11];
    const float* e1m  = (const float*)d_in[12];
    const float* e1v  = (const float*)d_in[13];
    const float* e2aw = (const float*)d_in[14];
    const float* e2ag = (const float*)d_in[15];
    const float* e2ab = (const float*)d_in[16];
    const float* e2am = (const float*)d_in[17];
    const float* e2av = (const float*)d_in[18];
    const float* e2bw = (const float*)d_in[19];
    const float* e2bg = (const float*)d_in[20];
    const float* e2bb = (const float*)d_in[21];
    const float* e2bm = (const float*)d_in[22];
    const float* e2bv = (const float*)d_in[23];

    float* out = (float*)d_out;

    const size_t PLANE = (size_t)32*66*66*64;    // u16 per plane (17.8 MB)
    u16* xhA  = (u16*)d_ws;
    u16* xhB  = xhA + PLANE;
    u16* g1   = xhB + PLANE;                     // 16.8 MB
    u16* Wt0f = g1 + (size_t)8388608;
    u16* Wt2f = Wt0f + 73728;
    u16* Wt1f = Wt2f + 73728;

    k_prep<<<128, 256, 0, stream>>>(e0w, e2aw, e1pw, Wt0f, Wt2f, Wt1f);
    k_to_nhwc<<<dim3(64, B_), 256, 0, stream>>>(x, wts, idxs, xhA, xhB);
    k_conv<<<dim3(32, B_), 256, 0, stream>>>(
        xhA, xhB, x, wts, idxs, Wt0f, Wt2f,
        e0g, e0b, e0m, e0v, e2ag, e2ab, e2am, e2av, out, g1);
    k_e1<<<dim3(32, B_), 256, 0, stream>>>(
        x, wts, idxs, e1dw, Wt1f, e1g, e1b, e1m, e1v, out);
    k_e2b<<<dim3(32, B_), 256, 0, stream>>>(
        g1, wts, idxs, e2bw, e2bg, e2bb, e2bm, e2bv, out);
}

// Round 10
// 110.752 us; speedup vs baseline: 1.2125x; 1.2125x over previous
//
#include <hip/hip_runtime.h>

#define B_  32
#define C_  128
#define CS  64
#define H_  64
#define W_  64
#define HW  (H_*W_)

typedef __attribute__((ext_vector_type(8))) short bf16x8_t;
typedef __attribute__((ext_vector_type(4))) float f32x4_t;
typedef unsigned short u16;
typedef unsigned int   u32;

__device__ __forceinline__ float silu_f(float v) { return v / (1.f + __expf(-v)); }

__device__ __forceinline__ u16 f2bf(float f) {
    u32 u = __float_as_uint(f);
    u = (u + 0x7FFFu + ((u >> 16) & 1u)) >> 16;   // RNE
    return (u16)u;
}
__device__ __forceinline__ float bf2f(u16 u) {
    return __uint_as_float(((u32)u) << 16);
}
__device__ __forceinline__ u32 pack2(float a, float b) {
    return (u32)f2bf(a) | ((u32)f2bf(b) << 16);
}

__device__ __forceinline__ void get_coeffs(const float* __restrict__ wts,
                                           const int* __restrict__ idxs, int b,
                                           float& c0, float& c1, float& c2, float& cid) {
    int   i0 = idxs[b*2+0], i1 = idxs[b*2+1];
    float w0 = wts[b*2+0],  w1 = wts[b*2+1];
    c0  = (i0==0?w0:0.f)   + (i1==0?w1:0.f);
    c1  = (i0==1?w0:0.f)   + (i1==1?w1:0.f);
    c2  = (i0==2?w0:0.f)   + (i1==2?w1:0.f);
    cid = (i0==3?0.1f:0.f) + (i1==3?0.1f:0.f);
}

// ---- weight prep: MFMA-fragment-ordered bf16 weights --------------------------
// Wt0f: e0  [tap9][kc2][cog8][lane64][8]   A[row=co=cog*16+(l&15)][k=kc*32+(l>>4)*8+j]
// Wt2f: e2a [tap9][kc4][cog4][lane64][8]
// Wt1f: e1pw[kc2][cog8][lane64][8]
__global__ __launch_bounds__(256) void k_prep(
    const float* __restrict__ e0w, const float* __restrict__ e2aw, const float* __restrict__ e1pw,
    u16* __restrict__ Wt0f, u16* __restrict__ Wt2f, u16* __restrict__ Wt1f)
{
    const int i0 = blockIdx.x*256 + threadIdx.x, stride = gridDim.x*256;
    for (int i = i0; i < 73728; i += stride) {
        int j = i&7, lane = (i>>3)&63, cog = (i>>9)&7, kc = (i>>12)&1, tap = i>>13;
        int co = cog*16 + (lane&15), ci = kc*32 + (lane>>4)*8 + j;
        Wt0f[i] = f2bf(e0w[(size_t)(co*64 + ci)*9 + tap]);
    }
    for (int i = i0; i < 73728; i += stride) {
        int j = i&7, lane = (i>>3)&63, cog = (i>>9)&3, kc = (i>>11)&3, tap = i>>13;
        int co = cog*16 + (lane&15), ci = kc*32 + (lane>>4)*8 + j;
        Wt2f[i] = f2bf(e2aw[(size_t)(co*128 + ci)*9 + tap]);
    }
    for (int i = i0; i < 8192; i += stride) {
        int j = i&7, lane = (i>>3)&63, cog = (i>>9)&7, kc = (i>>12)&1;
        int co = cog*16 + (lane&15), ci = kc*32 + (lane>>4)*8 + j;
        Wt1f[i] = f2bf(e1pw[(size_t)co*64 + ci]);
    }
}

// ---- NCHW fp32 -> two padded NHWC bf16 planes [b][66][66][64], zero borders ----
__global__ __launch_bounds__(256) void k_to_nhwc(
    const float* __restrict__ x, const float* __restrict__ wts, const int* __restrict__ idxs,
    u16* __restrict__ xhA, u16* __restrict__ xhB)
{
    const int b = blockIdx.y, h = blockIdx.x, t = threadIdx.x;
    float c0, c1, c2, cid;
    get_coeffs(wts, idxs, b, c0, c1, c2, cid);
    if (c0 == 0.f && c2 == 0.f) return;
    const int np = (c2 != 0.f) ? 2 : 1;
    const int chmax = np*64;

    __shared__ float ld[128*66];
    for (int i = t; i < chmax*16; i += 256) {
        int ch = i >> 4, q = i & 15;
        float4 v = *(const float4*)(x + ((size_t)(b*C_+ch))*HW + h*64 + q*4);
        float* p = &ld[ch*66 + q*4];
        p[0] = v.x; p[1] = v.y; p[2] = v.z; p[3] = v.w;
    }
    __syncthreads();

    const int px = t >> 2, sub = t & 3;
    const size_t base64 = ((size_t)(b*66 + h+1)*66 + (px+1))*64;
    for (int c = sub; c < chmax/8; c += 4) {
        uint4 v;
        u32 w[4];
        #pragma unroll
        for (int k = 0; k < 4; ++k)
            w[k] = pack2(ld[(c*8 + 2*k)*66 + px], ld[(c*8 + 2*k + 1)*66 + px]);
        v.x = w[0]; v.y = w[1]; v.z = w[2]; v.w = w[3];
        u16* dst = (c < 8) ? (xhA + base64 + c*8) : (xhB + base64 + (c-8)*8);
        *(uint4*)dst = v;
    }
    // zero border cols 0 and 65 of this row
    for (int i = t; i < 16*np; i += 256) {
        int pl = i >> 4, j = i & 15;
        int col = (j >> 3)*65, cg = j & 7;
        u16* ph = pl ? xhB : xhA;
        uint4 z; z.x = z.y = z.z = z.w = 0u;
        *(uint4*)(ph + ((size_t)(b*66 + h+1)*66 + col)*64 + cg*8) = z;
    }
    // zero border rows 0 / 65
    if (h == 0 || h == 63) {
        int r = (h == 0) ? 0 : 65;
        for (int i = t; i < 66*8*np; i += 256) {
            int pl = i / (66*8), j = i % (66*8);
            int col = j >> 3, cg = j & 7;
            u16* ph = pl ? xhB : xhA;
            uint4 z; z.x = z.y = z.z = z.w = 0u;
            *(uint4*)(ph + ((size_t)(b*66 + r)*66 + (size_t)col)*64 + cg*8) = z;
        }
    }
}

// ---- one K-pass over a staged 64-ch plane: 9 taps x 2 local kc ---------------
// TK = total kc per tap in weight layout; koff = kc offset of this pass.
template<int NCF, int NPF, int TK, int COUT>
__device__ __forceinline__ void conv_pass(
    const char* lin, const u16* __restrict__ wb, int koff,
    int rbase, int pxbase, int l15, int kg,
    f32x4_t (&acc)[NCF][NPF])
{
    bf16x8_t aC[NCF], aN[NCF];
    auto loadA = [&](int i, bf16x8_t* a) {   // i in [0,18)
        const int tap = i >> 1, kcl = i & 1;
        const u16* wt = wb + (size_t)((tap*TK + koff + kcl)*(COUT/16))*512;
        #pragma unroll
        for (int cf = 0; cf < NCF; ++cf)
            a[cf] = *(const bf16x8_t*)(wt + (cf << 9));
    };
    auto ldsB = [&](int i, int pf) -> bf16x8_t {
        const int tap = i >> 1, kcl = i & 1;
        const int dh = tap / 3, dwp = tap % 3;
        const int p = (rbase + dh)*66 + pxbase + pf*16 + l15 + dwp;
        u32 a = (u32)p*128 + (u32)kcl*64 + (u32)kg*16;
        a ^= ((u32)(p & 7)) << 4;
        return *(const bf16x8_t*)(lin + a);
    };

    loadA(0, aC);
    #pragma unroll
    for (int i = 0; i < 18; ++i) {
        bf16x8_t* ac = (i & 1) ? aN : aC;
        bf16x8_t* an = (i & 1) ? aC : aN;
        if (i + 1 < 18) loadA(i + 1, an);
        #pragma unroll
        for (int pf = 0; pf < NPF; ++pf) {
            bf16x8_t bfr = ldsB(i, pf);
            #pragma unroll
            for (int cf = 0; cf < NCF; ++cf)
                acc[cf][pf] = __builtin_amdgcn_mfma_f32_16x16x32_bf16(ac[cf], bfr, acc[cf][pf], 0, 0, 0);
        }
    }
}

// ---- merged conv kernel: grid (32 bands, B, 2). z=0 e0, z=1 e2a. --------------
// LDS 33.8 KB both paths -> 4 blocks/CU. 4 waves/block.
__global__ __launch_bounds__(256, 4) void k_conv(
    const u16* __restrict__ xhA, const u16* __restrict__ xhB, const float* __restrict__ x,
    const float* __restrict__ wts, const int* __restrict__ idxs,
    const u16* __restrict__ Wt0f, const u16* __restrict__ Wt2f,
    const float* __restrict__ e0g, const float* __restrict__ e0b,
    const float* __restrict__ e0m, const float* __restrict__ e0v,
    const float* __restrict__ e2ag, const float* __restrict__ e2ab,
    const float* __restrict__ e2am, const float* __restrict__ e2av,
    float* __restrict__ out, u16* __restrict__ g1)
{
    __shared__ char lin[33792];
    const int b = blockIdx.y, orow0 = blockIdx.x*2, t = threadIdx.x;
    float c0, c1, c2, cid;
    get_coeffs(wts, idxs, b, c0, c1, c2, cid);

    const int lane = t & 63, l15 = lane & 15, kg = lane >> 4, wv = t >> 6;
    const size_t src0 = ((size_t)(b*66 + orow0))*66*64;

    auto stage = [&](const u16* src) {
        const char* sp = (const char*)src;
        for (int d = t*16; d < 33792; d += 4096) {
            u32 s = (u32)d ^ ((((u32)d >> 7) & 7u) << 4);
            *(uint4*)(lin + d) = *(const uint4*)(sp + s);
        }
    };

    if (blockIdx.z == 0) {
        if (c0 == 0.f) {   // identity-only init of these 2 rows (all 128 ch)
            for (int i = t; i < 4096; i += 256) {
                int ch = i >> 5, q = i & 31;
                size_t o = ((size_t)(b*C_+ch))*HW + (size_t)orow0*64 + q*4;
                float4 ov;
                if (cid != 0.f) {
                    float4 xv = *(const float4*)(x + o);
                    ov.x = cid*xv.x; ov.y = cid*xv.y; ov.z = cid*xv.z; ov.w = cid*xv.w;
                } else { ov.x = ov.y = ov.z = ov.w = 0.f; }
                *(float4*)(out + o) = ov;
            }
            return;
        }
        stage(xhA + src0);
        __syncthreads();

        const int cw = wv >> 1, rw = wv & 1;
        const int cobase = cw*64;
        f32x4_t acc[4][4];
        #pragma unroll
        for (int cf = 0; cf < 4; ++cf)
            #pragma unroll
            for (int pf = 0; pf < 4; ++pf)
                acc[cf][pf] = (f32x4_t){0.f, 0.f, 0.f, 0.f};

        const u16* wb = Wt0f + (size_t)(cobase >> 4)*512 + (size_t)lane*8;
        conv_pass<4, 4, 2, 128>(lin, wb, 0, rw, 0, l15, kg, acc);

        #pragma unroll
        for (int cf = 0; cf < 4; ++cf) {
            float sarr[4], tarr[4];
            #pragma unroll
            for (int r = 0; r < 4; ++r) {
                int co = cobase + cf*16 + kg*4 + r;
                float s = e0g[co] * rsqrtf(e0v[co] + 1e-5f);
                sarr[r] = s; tarr[r] = e0b[co] - e0m[co]*s;
            }
            #pragma unroll
            for (int pf = 0; pf < 4; ++pf) {
                size_t rowoff = (size_t)(orow0 + rw)*64 + pf*16 + l15;
                #pragma unroll
                for (int r = 0; r < 4; ++r) {
                    int co = cobase + cf*16 + kg*4 + r;
                    float v = silu_f(acc[cf][pf][r]*sarr[r] + tarr[r]);
                    size_t o = ((size_t)(b*C_+co))*HW + rowoff;
                    float idv = (cid != 0.f) ? cid*x[o] : 0.f;
                    out[o] = c0*v + idv;
                }
            }
        }
    } else {
        if (c2 == 0.f) return;

        const int rw = wv >> 1, pw = wv & 1;
        const int pxbase = pw*32;
        f32x4_t acc[4][2];
        #pragma unroll
        for (int cf = 0; cf < 4; ++cf)
            #pragma unroll
            for (int pf = 0; pf < 2; ++pf)
                acc[cf][pf] = (f32x4_t){0.f, 0.f, 0.f, 0.f};

        const u16* wb = Wt2f + (size_t)lane*8;

        stage(xhA + src0);
        __syncthreads();
        conv_pass<4, 2, 4, 64>(lin, wb, 0, rw, pxbase, l15, kg, acc);
        __syncthreads();
        stage(xhB + src0);
        __syncthreads();
        conv_pass<4, 2, 4, 64>(lin, wb, 2, rw, pxbase, l15, kg, acc);

        #pragma unroll
        for (int cf = 0; cf < 4; ++cf) {
            float sarr[4], tarr[4];
            #pragma unroll
            for (int r = 0; r < 4; ++r) {
                int co = cf*16 + kg*4 + r;
                float s = e2ag[co] * rsqrtf(e2av[co] + 1e-5f);
                sarr[r] = s; tarr[r] = e2ab[co] - e2am[co]*s;
            }
            #pragma unroll
            for (int pf = 0; pf < 2; ++pf) {
                size_t rowoff = (size_t)(orow0 + rw)*64 + pxbase + pf*16 + l15;
                #pragma unroll
                for (int r = 0; r < 4; ++r) {
                    int co = cf*16 + kg*4 + r;
                    float v = silu_f(acc[cf][pf][r]*sarr[r] + tarr[r]);
                    g1[((size_t)(b*CS+co))*HW + rowoff] = f2bf(v);
                }
            }
        }
    }
}

// ---- fused e1: dw5x5(x_ir) in LDS -> pw1x1 MFMA -> BN/SiLU -> out += c1*e1 ----
__global__ __launch_bounds__(256) void k_e1(
    const float* __restrict__ x, const float* __restrict__ wts, const int* __restrict__ idxs,
    const float* __restrict__ dww, const u16* __restrict__ Wt1f,
    const float* __restrict__ gg, const float* __restrict__ bb,
    const float* __restrict__ mm, const float* __restrict__ vv,
    float* __restrict__ out)
{
    const int b = blockIdx.y, band = blockIdx.x, t = threadIdx.x;
    const int orow0 = band*2;

    float c0, c1, c2, cid;
    get_coeffs(wts, idxs, b, c0, c1, c2, cid);
    if (c1 == 0.f) return;

    __shared__ u16  lin[6*64*70];   // [row6][ch64][col70] cols -2..65 (+pad), bf16
    __shared__ u16  lout[128*72];   // [px128][ci72pad] bf16
    __shared__ float wl[64*26];

    for (int i = t; i < 64*25; i += 256) wl[(i/25)*26 + (i%25)] = dww[i];
    for (int i = t; i < 6*64*16; i += 256) {
        int q = i & 15, ch = (i >> 4) & 63, r = i >> 10;
        int hh = orow0 - 2 + r;
        u32 w0 = 0u, w1 = 0u;
        if (hh >= 0 && hh < H_) {
            float4 v = *(const float4*)(x + ((size_t)(b*C_ + CS + ch))*HW + hh*64 + q*4);
            w0 = pack2(v.x, v.y); w1 = pack2(v.z, v.w);
        }
        u32* dst = (u32*)&lin[(r*64 + ch)*70 + 2 + q*4];
        dst[0] = w0; dst[1] = w1;
    }
    for (int i = t; i < 6*64; i += 256) {
        int ch = i & 63, r = i >> 6;
        *(u32*)&lin[(r*64 + ch)*70]      = 0u;
        u32* e = (u32*)&lin[(r*64 + ch)*70 + 66];
        e[0] = 0u; e[1] = 0u;
    }
    __syncthreads();

    const int lane = t & 63, chl = lane & 15, cs = lane >> 4;
    const int wv = t >> 6, outrow = wv & 1, chhalf = wv >> 1;

    #pragma unroll
    for (int chi = 0; chi < 2; ++chi) {
        const int ch = chhalf*32 + chl + chi*16;
        const float* wch = &wl[ch*26];
        float accp[16];
        #pragma unroll
        for (int p = 0; p < 16; ++p) accp[p] = 0.f;
        #pragma unroll
        for (int kh = 0; kh < 5; ++kh) {
            const u16* src = &lin[((outrow + kh)*64 + ch)*70 + cs*16];
            float rb[20];
            #pragma unroll
            for (int k = 0; k < 10; ++k) {
                u32 u = *(const u32*)(src + 2*k);
                rb[2*k]   = __uint_as_float(u << 16);
                rb[2*k+1] = __uint_as_float(u & 0xFFFF0000u);
            }
            #pragma unroll
            for (int kw = 0; kw < 5; ++kw) {
                float wvv = wch[kh*5 + kw];
                #pragma unroll
                for (int p = 0; p < 16; ++p) accp[p] += rb[p+kw]*wvv;
            }
        }
        const int px0 = outrow*64 + cs*16;
        #pragma unroll
        for (int p = 0; p < 16; ++p) lout[(px0+p)*72 + ch] = f2bf(accp[p]);
    }
    __syncthreads();

    const int l15 = lane & 15, kg = lane >> 4;
    const int cw = wv >> 1, pwv = wv & 1;
    f32x4_t acc[4][4];
    #pragma unroll
    for (int cf = 0; cf < 4; ++cf)
        #pragma unroll
        for (int pf = 0; pf < 4; ++pf)
            acc[cf][pf] = (f32x4_t){0.f, 0.f, 0.f, 0.f};

    #pragma unroll
    for (int kc = 0; kc < 2; ++kc) {
        const u16* wt = Wt1f + (((size_t)(kc*8 + cw*4)) << 9) + lane*8;
        bf16x8_t af[4];
        #pragma unroll
        for (int cf = 0; cf < 4; ++cf) af[cf] = *(const bf16x8_t*)(wt + (cf << 9));
        const int k0 = kc*32 + kg*8;
        #pragma unroll
        for (int pf = 0; pf < 4; ++pf) {
            bf16x8_t bfr = *(const bf16x8_t*)&lout[(pwv*64 + pf*16 + l15)*72 + k0];
            #pragma unroll
            for (int cf = 0; cf < 4; ++cf)
                acc[cf][pf] = __builtin_amdgcn_mfma_f32_16x16x32_bf16(af[cf], bfr, acc[cf][pf], 0, 0, 0);
        }
    }

    #pragma unroll
    for (int cf = 0; cf < 4; ++cf) {
        float sarr[4], tarr[4];
        #pragma unroll
        for (int r = 0; r < 4; ++r) {
            int co = cw*64 + cf*16 + kg*4 + r;
            float s = gg[co] * rsqrtf(vv[co] + 1e-5f);
            sarr[r] = s; tarr[r] = bb[co] - mm[co]*s;
        }
        #pragma unroll
        for (int pf = 0; pf < 4; ++pf) {
            int px = pwv*64 + pf*16 + l15;
            size_t rowoff = (size_t)(orow0 + (px>>6))*64 + (px&63);
            #pragma unroll
            for (int r = 0; r < 4; ++r) {
                int co = cw*64 + cf*16 + kg*4 + r;
                float v = silu_f(acc[cf][pf][r]*sarr[r] + tarr[r]);
                out[((size_t)(b*C_+co))*HW + rowoff] += c1*v;
            }
        }
    }
}

// ---- e2b: out[:, :64] += c2*g1 ; out[:, 64:] += c2*silu(bn(dw5x5(g1))) --------
__global__ __launch_bounds__(256) void k_e2b(
    const u16* __restrict__ g1, const float* __restrict__ wts, const int* __restrict__ idxs,
    const float* __restrict__ dww, const float* __restrict__ gg, const float* __restrict__ bb,
    const float* __restrict__ mm, const float* __restrict__ vv, float* __restrict__ out)
{
    const int b = blockIdx.y, band = blockIdx.x, t = threadIdx.x;
    const int orow0 = band*2;

    float c0, c1, c2, cid;
    get_coeffs(wts, idxs, b, c0, c1, c2, cid);
    if (c2 == 0.f) return;

    __shared__ u16  lin[6*64*70];
    __shared__ float wl[64*26];

    for (int i = t; i < 64*25; i += 256) wl[(i/25)*26 + (i%25)] = dww[i];
    for (int i = t; i < 6*64*16; i += 256) {
        int q = i & 15, ch = (i >> 4) & 63, r = i >> 10;
        int hh = orow0 - 2 + r;
        u32 w0 = 0u, w1 = 0u;
        if (hh >= 0 && hh < H_) {
            const u32* src = (const u32*)(g1 + ((size_t)(b*CS+ch))*HW + hh*64 + q*4);
            w0 = src[0]; w1 = src[1];
        }
        u32* dst = (u32*)&lin[(r*64 + ch)*70 + 2 + q*4];
        dst[0] = w0; dst[1] = w1;
    }
    for (int i = t; i < 6*64; i += 256) {
        int ch = i & 63, r = i >> 6;
        *(u32*)&lin[(r*64 + ch)*70] = 0u;
        u32* e = (u32*)&lin[(r*64 + ch)*70 + 66];
        e[0] = 0u; e[1] = 0u;
    }
    __syncthreads();

    // out[:, :64] += c2*g1 for the 2 center rows (lin rows 2,3)
    for (int i = t; i < 2*64*16; i += 256) {
        int q = i & 15, ch = (i >> 4) & 63, r = i >> 10;
        const u16* src = &lin[((r+2)*64 + ch)*70 + 2 + q*4];
        float* op = out + ((size_t)(b*C_+ch))*HW + (size_t)(orow0+r)*64 + q*4;
        float4 ov = *(float4*)op;
        ov.x += c2*bf2f(src[0]); ov.y += c2*bf2f(src[1]);
        ov.z += c2*bf2f(src[2]); ov.w += c2*bf2f(src[3]);
        *(float4*)op = ov;
    }

    const int lane = t & 63, chl = lane & 15, cs = lane >> 4;
    const int wv = t >> 6, outrow = wv & 1, chhalf = wv >> 1;

    #pragma unroll
    for (int chi = 0; chi < 2; ++chi) {
        const int ch = chhalf*32 + chl + chi*16;
        const float* wch = &wl[ch*26];
        float accp[16];
        #pragma unroll
        for (int p = 0; p < 16; ++p) accp[p] = 0.f;
        #pragma unroll
        for (int kh = 0; kh < 5; ++kh) {
            const u16* src = &lin[((outrow + kh)*64 + ch)*70 + cs*16];
            float rb[20];
            #pragma unroll
            for (int k = 0; k < 10; ++k) {
                u32 u = *(const u32*)(src + 2*k);
                rb[2*k]   = __uint_as_float(u << 16);
                rb[2*k+1] = __uint_as_float(u & 0xFFFF0000u);
            }
            #pragma unroll
            for (int kw = 0; kw < 5; ++kw) {
                float wvv = wch[kh*5 + kw];
                #pragma unroll
                for (int p = 0; p < 16; ++p) accp[p] += rb[p+kw]*wvv;
            }
        }
        float s = gg[ch] * rsqrtf(vv[ch] + 1e-5f);
        float tt = bb[ch] - mm[ch]*s;
        float* op = out + ((size_t)(b*C_ + CS + ch))*HW + (size_t)(orow0+outrow)*64 + cs*16;
        #pragma unroll
        for (int q = 0; q < 4; ++q) {
            float4 ov = *(float4*)(op + q*4);
            ov.x += c2*silu_f(accp[q*4+0]*s + tt);
            ov.y += c2*silu_f(accp[q*4+1]*s + tt);
            ov.z += c2*silu_f(accp[q*4+2]*s + tt);
            ov.w += c2*silu_f(accp[q*4+3]*s + tt);
            *(float4*)(op + q*4) = ov;
        }
    }
}

extern "C" void kernel_launch(void* const* d_in, const int* in_sizes, int n_in,
                              void* d_out, int out_size, void* d_ws, size_t ws_size,
                              hipStream_t stream) {
    const float* x    = (const float*)d_in[0];
    const float* wts  = (const float*)d_in[1];
    const int*   idxs = (const int*)  d_in[2];
    const float* e0w  = (const float*)d_in[3];
    const float* e0g  = (const float*)d_in[4];
    const float* e0b  = (const float*)d_in[5];
    const float* e0m  = (const float*)d_in[6];
    const float* e0v  = (const float*)d_in[7];
    const float* e1dw = (const float*)d_in[8];
    const float* e1pw = (const float*)d_in[9];
    const float* e1g  = (const float*)d_in[10];
    const float* e1b  = (const float*)d_in[11];
    const float* e1m  = (const float*)d_in[12];
    const float* e1v  = (const float*)d_in[13];
    const float* e2aw = (const float*)d_in[14];
    const float* e2ag = (const float*)d_in[15];
    const float* e2ab = (const float*)d_in[16];
    const float* e2am = (const float*)d_in[17];
    const float* e2av = (const float*)d_in[18];
    const float* e2bw = (const float*)d_in[19];
    const float* e2bg = (const float*)d_in[20];
    const float* e2bb = (const float*)d_in[21];
    const float* e2bm = (const float*)d_in[22];
    const float* e2bv = (const float*)d_in[23];

    float* out = (float*)d_out;

    const size_t PLANE = (size_t)32*66*66*64;    // u16 per plane (17.8 MB)
    u16* xhA  = (u16*)d_ws;
    u16* xhB  = xhA + PLANE;
    u16* g1   = xhB + PLANE;                     // 16.8 MB
    u16* Wt0f = g1 + (size_t)8388608;
    u16* Wt2f = Wt0f + 73728;
    u16* Wt1f = Wt2f + 73728;

    k_prep<<<128, 256, 0, stream>>>(e0w, e2aw, e1pw, Wt0f, Wt2f, Wt1f);
    k_to_nhwc<<<dim3(64, B_), 256, 0, stream>>>(x, wts, idxs, xhA, xhB);
    k_conv<<<dim3(32, B_, 2), 256, 0, stream>>>(
        xhA, xhB, x, wts, idxs, Wt0f, Wt2f,
        e0g, e0b, e0m, e0v, e2ag, e2ab, e2am, e2av, out, g1);
    k_e1<<<dim3(32, B_), 256, 0, stream>>>(
        x, wts, idxs, e1dw, Wt1f, e1g, e1b, e1m, e1v, out);
    k_e2b<<<dim3(32, B_), 256, 0, stream>>>(
        g1, wts, idxs, e2bw, e2bg, e2bb, e2bm, e2bv, out);
}

// Round 11
// 107.906 us; speedup vs baseline: 1.2445x; 1.0264x over previous
//
#include <hip/hip_runtime.h>

#define B_  32
#define C_  128
#define CS  64
#define H_  64
#define W_  64
#define HW  (H_*W_)

typedef __attribute__((ext_vector_type(8))) short bf16x8_t;
typedef __attribute__((ext_vector_type(4))) float f32x4_t;
typedef unsigned short u16;
typedef unsigned int   u32;

__device__ __forceinline__ float silu_f(float v) { return v / (1.f + __expf(-v)); }

__device__ __forceinline__ u16 f2bf(float f) {
    u32 u = __float_as_uint(f);
    u = (u + 0x7FFFu + ((u >> 16) & 1u)) >> 16;   // RNE
    return (u16)u;
}
__device__ __forceinline__ float bf2f(u16 u) {
    return __uint_as_float(((u32)u) << 16);
}
__device__ __forceinline__ u32 pack2(float a, float b) {
    return (u32)f2bf(a) | ((u32)f2bf(b) << 16);
}

__device__ __forceinline__ void get_coeffs(const float* __restrict__ wts,
                                           const int* __restrict__ idxs, int b,
                                           float& c0, float& c1, float& c2, float& cid) {
    int   i0 = idxs[b*2+0], i1 = idxs[b*2+1];
    float w0 = wts[b*2+0],  w1 = wts[b*2+1];
    c0  = (i0==0?w0:0.f)   + (i1==0?w1:0.f);
    c1  = (i0==1?w0:0.f)   + (i1==1?w1:0.f);
    c2  = (i0==2?w0:0.f)   + (i1==2?w1:0.f);
    cid = (i0==3?0.1f:0.f) + (i1==3?0.1f:0.f);
}

// ---- weight prep: MFMA-fragment-ordered bf16 weights --------------------------
__global__ __launch_bounds__(256) void k_prep(
    const float* __restrict__ e0w, const float* __restrict__ e2aw, const float* __restrict__ e1pw,
    u16* __restrict__ Wt0f, u16* __restrict__ Wt2f, u16* __restrict__ Wt1f)
{
    const int i0 = blockIdx.x*256 + threadIdx.x, stride = gridDim.x*256;
    for (int i = i0; i < 73728; i += stride) {
        int j = i&7, lane = (i>>3)&63, cog = (i>>9)&7, kc = (i>>12)&1, tap = i>>13;
        int co = cog*16 + (lane&15), ci = kc*32 + (lane>>4)*8 + j;
        Wt0f[i] = f2bf(e0w[(size_t)(co*64 + ci)*9 + tap]);
    }
    for (int i = i0; i < 73728; i += stride) {
        int j = i&7, lane = (i>>3)&63, cog = (i>>9)&3, kc = (i>>11)&3, tap = i>>13;
        int co = cog*16 + (lane&15), ci = kc*32 + (lane>>4)*8 + j;
        Wt2f[i] = f2bf(e2aw[(size_t)(co*128 + ci)*9 + tap]);
    }
    for (int i = i0; i < 8192; i += stride) {
        int j = i&7, lane = (i>>3)&63, cog = (i>>9)&7, kc = (i>>12)&1;
        int co = cog*16 + (lane&15), ci = kc*32 + (lane>>4)*8 + j;
        Wt1f[i] = f2bf(e1pw[(size_t)co*64 + ci]);
    }
}

// ---- NCHW fp32 -> two padded NHWC bf16 planes [b][66][66][64], zero borders ----
__global__ __launch_bounds__(256) void k_to_nhwc(
    const float* __restrict__ x, const float* __restrict__ wts, const int* __restrict__ idxs,
    u16* __restrict__ xhA, u16* __restrict__ xhB)
{
    const int b = blockIdx.y, h = blockIdx.x, t = threadIdx.x;
    float c0, c1, c2, cid;
    get_coeffs(wts, idxs, b, c0, c1, c2, cid);
    if (c0 == 0.f && c2 == 0.f) return;
    const int np = (c2 != 0.f) ? 2 : 1;
    const int chmax = np*64;

    __shared__ float ld[128*66];
    for (int i = t; i < chmax*16; i += 256) {
        int ch = i >> 4, q = i & 15;
        float4 v = *(const float4*)(x + ((size_t)(b*C_+ch))*HW + h*64 + q*4);
        float* p = &ld[ch*66 + q*4];
        p[0] = v.x; p[1] = v.y; p[2] = v.z; p[3] = v.w;
    }
    __syncthreads();

    const int px = t >> 2, sub = t & 3;
    const size_t base64 = ((size_t)(b*66 + h+1)*66 + (px+1))*64;
    for (int c = sub; c < chmax/8; c += 4) {
        uint4 v;
        u32 w[4];
        #pragma unroll
        for (int k = 0; k < 4; ++k)
            w[k] = pack2(ld[(c*8 + 2*k)*66 + px], ld[(c*8 + 2*k + 1)*66 + px]);
        v.x = w[0]; v.y = w[1]; v.z = w[2]; v.w = w[3];
        u16* dst = (c < 8) ? (xhA + base64 + c*8) : (xhB + base64 + (c-8)*8);
        *(uint4*)dst = v;
    }
    for (int i = t; i < 16*np; i += 256) {
        int pl = i >> 4, j = i & 15;
        int col = (j >> 3)*65, cg = j & 7;
        u16* ph = pl ? xhB : xhA;
        uint4 z; z.x = z.y = z.z = z.w = 0u;
        *(uint4*)(ph + ((size_t)(b*66 + h+1)*66 + col)*64 + cg*8) = z;
    }
    if (h == 0 || h == 63) {
        int r = (h == 0) ? 0 : 65;
        for (int i = t; i < 66*8*np; i += 256) {
            int pl = i / (66*8), j = i % (66*8);
            int col = j >> 3, cg = j & 7;
            u16* ph = pl ? xhB : xhA;
            uint4 z; z.x = z.y = z.z = z.w = 0u;
            *(uint4*)(ph + ((size_t)(b*66 + r)*66 + (size_t)col)*64 + cg*8) = z;
        }
    }
}

// ---- one K-pass over a staged 64-ch plane, asm A-loads + counted vmcnt --------
// 18 iters (9 taps x 2 local kc). A-loads 3-deep in flight (8-12 outstanding);
// iter i waits only for loads issued at i (2 iters ago) -> L2 latency hidden.
template<int NCF, int NPF, int TK, int COUT>
__device__ __forceinline__ void conv_pass(
    const char* lin, const u16* __restrict__ wb, int koff,
    int rbase, int pxbase, int l15, int kg,
    f32x4_t (&acc)[NCF][NPF])
{
    bf16x8_t A0[NCF], A1[NCF], A2[NCF];

    auto issueA = [&](int i, bf16x8_t (&dst)[NCF]) {
        const int tap = i >> 1, kcl = i & 1;
        const u16* wt = wb + (size_t)((tap*TK + koff + kcl)*(COUT/16))*512;
        #pragma unroll
        for (int cf = 0; cf < NCF; ++cf)
            asm volatile("global_load_dwordx4 %0, %1, off"
                         : "=v"(dst[cf]) : "v"(wt + ((size_t)cf << 9)));
    };
    auto ldsB = [&](int i, int pf) -> bf16x8_t {
        const int tap = i >> 1, kcl = i & 1;
        const int dh = tap / 3, dwp = tap % 3;
        const int p = (rbase + dh)*66 + pxbase + pf*16 + l15 + dwp;
        u32 a = (u32)p*128 + (u32)kcl*64 + (u32)kg*16;
        a ^= ((u32)(p & 7)) << 4;
        return *(const bf16x8_t*)(lin + a);
    };

    issueA(0, A0);
    issueA(1, A1);
    #pragma unroll
    for (int i = 0; i < 18; ++i) {
        if (i + 2 < 18) {
            const int s = (i + 2) % 3;
            if (s == 0)      issueA(i + 2, A0);
            else if (s == 1) issueA(i + 2, A1);
            else             issueA(i + 2, A2);
        }
        if (i < 16)       asm volatile("s_waitcnt vmcnt(8)" ::: "memory");
        else if (i == 16) asm volatile("s_waitcnt vmcnt(4)" ::: "memory");
        else              asm volatile("s_waitcnt vmcnt(0)" ::: "memory");
        __builtin_amdgcn_sched_barrier(0);
        bf16x8_t* ac = (i % 3 == 0) ? A0 : ((i % 3 == 1) ? A1 : A2);
        #pragma unroll
        for (int pf = 0; pf < NPF; ++pf) {
            bf16x8_t bfr = ldsB(i, pf);
            #pragma unroll
            for (int cf = 0; cf < NCF; ++cf)
                acc[cf][pf] = __builtin_amdgcn_mfma_f32_16x16x32_bf16(ac[cf], bfr, acc[cf][pf], 0, 0, 0);
        }
    }
}

// ---- merged conv kernel: grid (32 bands, B, 2). z=0 e0, z=1 e2a. --------------
__global__ __launch_bounds__(256, 3) void k_conv(
    const u16* __restrict__ xhA, const u16* __restrict__ xhB, const float* __restrict__ x,
    const float* __restrict__ wts, const int* __restrict__ idxs,
    const u16* __restrict__ Wt0f, const u16* __restrict__ Wt2f,
    const float* __restrict__ e0g, const float* __restrict__ e0b,
    const float* __restrict__ e0m, const float* __restrict__ e0v,
    const float* __restrict__ e2ag, const float* __restrict__ e2ab,
    const float* __restrict__ e2am, const float* __restrict__ e2av,
    float* __restrict__ out, u16* __restrict__ g1)
{
    __shared__ char lin[33792];
    const int b = blockIdx.y, orow0 = blockIdx.x*2, t = threadIdx.x;
    float c0, c1, c2, cid;
    get_coeffs(wts, idxs, b, c0, c1, c2, cid);

    const int lane = t & 63, l15 = lane & 15, kg = lane >> 4, wv = t >> 6;
    const size_t src0 = ((size_t)(b*66 + orow0))*66*64;

    auto stage = [&](const u16* src) {
        const char* sp = (const char*)src;
        for (int d = t*16; d < 33792; d += 4096) {
            u32 s = (u32)d ^ ((((u32)d >> 7) & 7u) << 4);
            *(uint4*)(lin + d) = *(const uint4*)(sp + s);
        }
    };

    if (blockIdx.z == 0) {
        if (c0 == 0.f) {   // identity-only init of these 2 rows (all 128 ch)
            for (int i = t; i < 4096; i += 256) {
                int ch = i >> 5, q = i & 31;
                size_t o = ((size_t)(b*C_+ch))*HW + (size_t)orow0*64 + q*4;
                float4 ov;
                if (cid != 0.f) {
                    float4 xv = *(const float4*)(x + o);
                    ov.x = cid*xv.x; ov.y = cid*xv.y; ov.z = cid*xv.z; ov.w = cid*xv.w;
                } else { ov.x = ov.y = ov.z = ov.w = 0.f; }
                *(float4*)(out + o) = ov;
            }
            return;
        }
        stage(xhA + src0);
        __syncthreads();

        const int cw = wv >> 1, rw = wv & 1;
        const int cobase = cw*64;
        f32x4_t acc[4][4];
        #pragma unroll
        for (int cf = 0; cf < 4; ++cf)
            #pragma unroll
            for (int pf = 0; pf < 4; ++pf)
                acc[cf][pf] = (f32x4_t){0.f, 0.f, 0.f, 0.f};

        const u16* wb = Wt0f + (size_t)(cobase >> 4)*512 + (size_t)lane*8;
        conv_pass<4, 4, 2, 128>(lin, wb, 0, rw, 0, l15, kg, acc);

        #pragma unroll
        for (int cf = 0; cf < 4; ++cf) {
            float sarr[4], tarr[4];
            #pragma unroll
            for (int r = 0; r < 4; ++r) {
                int co = cobase + cf*16 + kg*4 + r;
                float s = e0g[co] * rsqrtf(e0v[co] + 1e-5f);
                sarr[r] = s; tarr[r] = e0b[co] - e0m[co]*s;
            }
            #pragma unroll
            for (int pf = 0; pf < 4; ++pf) {
                size_t rowoff = (size_t)(orow0 + rw)*64 + pf*16 + l15;
                #pragma unroll
                for (int r = 0; r < 4; ++r) {
                    int co = cobase + cf*16 + kg*4 + r;
                    float v = silu_f(acc[cf][pf][r]*sarr[r] + tarr[r]);
                    size_t o = ((size_t)(b*C_+co))*HW + rowoff;
                    float idv = (cid != 0.f) ? cid*x[o] : 0.f;
                    out[o] = c0*v + idv;
                }
            }
        }
    } else {
        if (c2 == 0.f) return;

        const int rw = wv >> 1, pw = wv & 1;
        const int pxbase = pw*32;
        f32x4_t acc[4][2];
        #pragma unroll
        for (int cf = 0; cf < 4; ++cf)
            #pragma unroll
            for (int pf = 0; pf < 2; ++pf)
                acc[cf][pf] = (f32x4_t){0.f, 0.f, 0.f, 0.f};

        const u16* wb = Wt2f + (size_t)lane*8;

        stage(xhA + src0);
        __syncthreads();
        conv_pass<4, 2, 4, 64>(lin, wb, 0, rw, pxbase, l15, kg, acc);
        __syncthreads();
        stage(xhB + src0);
        __syncthreads();
        conv_pass<4, 2, 4, 64>(lin, wb, 2, rw, pxbase, l15, kg, acc);

        #pragma unroll
        for (int cf = 0; cf < 4; ++cf) {
            float sarr[4], tarr[4];
            #pragma unroll
            for (int r = 0; r < 4; ++r) {
                int co = cf*16 + kg*4 + r;
                float s = e2ag[co] * rsqrtf(e2av[co] + 1e-5f);
                sarr[r] = s; tarr[r] = e2ab[co] - e2am[co]*s;
            }
            #pragma unroll
            for (int pf = 0; pf < 2; ++pf) {
                size_t rowoff = (size_t)(orow0 + rw)*64 + pxbase + pf*16 + l15;
                #pragma unroll
                for (int r = 0; r < 4; ++r) {
                    int co = cf*16 + kg*4 + r;
                    float v = silu_f(acc[cf][pf][r]*sarr[r] + tarr[r]);
                    g1[((size_t)(b*CS+co))*HW + rowoff] = f2bf(v);
                }
            }
        }
    }
}

// ---- fused e1: dw5x5(x_ir) in LDS -> pw1x1 MFMA -> BN/SiLU -> out += c1*e1 ----
__global__ __launch_bounds__(256) void k_e1(
    const float* __restrict__ x, const float* __restrict__ wts, const int* __restrict__ idxs,
    const float* __restrict__ dww, const u16* __restrict__ Wt1f,
    const float* __restrict__ gg, const float* __restrict__ bb,
    const float* __restrict__ mm, const float* __restrict__ vv,
    float* __restrict__ out)
{
    const int b = blockIdx.y, band = blockIdx.x, t = threadIdx.x;
    const int orow0 = band*2;

    float c0, c1, c2, cid;
    get_coeffs(wts, idxs, b, c0, c1, c2, cid);
    if (c1 == 0.f) return;

    __shared__ u16  lin[6*64*70];   // [row6][ch64][col70] cols -2..65 (+pad), bf16
    __shared__ u16  lout[128*72];   // [px128][ci72pad] bf16
    __shared__ float wl[64*26];

    for (int i = t; i < 64*25; i += 256) wl[(i/25)*26 + (i%25)] = dww[i];
    for (int i = t; i < 6*64*16; i += 256) {
        int q = i & 15, ch = (i >> 4) & 63, r = i >> 10;
        int hh = orow0 - 2 + r;
        u32 w0 = 0u, w1 = 0u;
        if (hh >= 0 && hh < H_) {
            float4 v = *(const float4*)(x + ((size_t)(b*C_ + CS + ch))*HW + hh*64 + q*4);
            w0 = pack2(v.x, v.y); w1 = pack2(v.z, v.w);
        }
        u32* dst = (u32*)&lin[(r*64 + ch)*70 + 2 + q*4];
        dst[0] = w0; dst[1] = w1;
    }
    for (int i = t; i < 6*64; i += 256) {
        int ch = i & 63, r = i >> 6;
        *(u32*)&lin[(r*64 + ch)*70]      = 0u;
        u32* e = (u32*)&lin[(r*64 + ch)*70 + 66];
        e[0] = 0u; e[1] = 0u;
    }
    __syncthreads();

    const int lane = t & 63, chl = lane & 15, cs = lane >> 4;
    const int wv = t >> 6, outrow = wv & 1, chhalf = wv >> 1;

    #pragma unroll
    for (int chi = 0; chi < 2; ++chi) {
        const int ch = chhalf*32 + chl + chi*16;
        const float* wch = &wl[ch*26];
        float accp[16];
        #pragma unroll
        for (int p = 0; p < 16; ++p) accp[p] = 0.f;
        #pragma unroll
        for (int kh = 0; kh < 5; ++kh) {
            const u16* src = &lin[((outrow + kh)*64 + ch)*70 + cs*16];
            float rb[20];
            #pragma unroll
            for (int k = 0; k < 10; ++k) {
                u32 u = *(const u32*)(src + 2*k);
                rb[2*k]   = __uint_as_float(u << 16);
                rb[2*k+1] = __uint_as_float(u & 0xFFFF0000u);
            }
            #pragma unroll
            for (int kw = 0; kw < 5; ++kw) {
                float wvv = wch[kh*5 + kw];
                #pragma unroll
                for (int p = 0; p < 16; ++p) accp[p] += rb[p+kw]*wvv;
            }
        }
        const int px0 = outrow*64 + cs*16;
        #pragma unroll
        for (int p = 0; p < 16; ++p) lout[(px0+p)*72 + ch] = f2bf(accp[p]);
    }
    __syncthreads();

    const int l15 = lane & 15, kg = lane >> 4;
    const int cw = wv >> 1, pwv = wv & 1;
    f32x4_t acc[4][4];
    #pragma unroll
    for (int cf = 0; cf < 4; ++cf)
        #pragma unroll
        for (int pf = 0; pf < 4; ++pf)
            acc[cf][pf] = (f32x4_t){0.f, 0.f, 0.f, 0.f};

    #pragma unroll
    for (int kc = 0; kc < 2; ++kc) {
        const u16* wt = Wt1f + (((size_t)(kc*8 + cw*4)) << 9) + lane*8;
        bf16x8_t af[4];
        #pragma unroll
        for (int cf = 0; cf < 4; ++cf) af[cf] = *(const bf16x8_t*)(wt + (cf << 9));
        const int k0 = kc*32 + kg*8;
        #pragma unroll
        for (int pf = 0; pf < 4; ++pf) {
            bf16x8_t bfr = *(const bf16x8_t*)&lout[(pwv*64 + pf*16 + l15)*72 + k0];
            #pragma unroll
            for (int cf = 0; cf < 4; ++cf)
                acc[cf][pf] = __builtin_amdgcn_mfma_f32_16x16x32_bf16(af[cf], bfr, acc[cf][pf], 0, 0, 0);
        }
    }

    #pragma unroll
    for (int cf = 0; cf < 4; ++cf) {
        float sarr[4], tarr[4];
        #pragma unroll
        for (int r = 0; r < 4; ++r) {
            int co = cw*64 + cf*16 + kg*4 + r;
            float s = gg[co] * rsqrtf(vv[co] + 1e-5f);
            sarr[r] = s; tarr[r] = bb[co] - mm[co]*s;
        }
        #pragma unroll
        for (int pf = 0; pf < 4; ++pf) {
            int px = pwv*64 + pf*16 + l15;
            size_t rowoff = (size_t)(orow0 + (px>>6))*64 + (px&63);
            #pragma unroll
            for (int r = 0; r < 4; ++r) {
                int co = cw*64 + cf*16 + kg*4 + r;
                float v = silu_f(acc[cf][pf][r]*sarr[r] + tarr[r]);
                out[((size_t)(b*C_+co))*HW + rowoff] += c1*v;
            }
        }
    }
}

// ---- e2b: out[:, :64] += c2*g1 ; out[:, 64:] += c2*silu(bn(dw5x5(g1))) --------
__global__ __launch_bounds__(256) void k_e2b(
    const u16* __restrict__ g1, const float* __restrict__ wts, const int* __restrict__ idxs,
    const float* __restrict__ dww, const float* __restrict__ gg, const float* __restrict__ bb,
    const float* __restrict__ mm, const float* __restrict__ vv, float* __restrict__ out)
{
    const int b = blockIdx.y, band = blockIdx.x, t = threadIdx.x;
    const int orow0 = band*2;

    float c0, c1, c2, cid;
    get_coeffs(wts, idxs, b, c0, c1, c2, cid);
    if (c2 == 0.f) return;

    __shared__ u16  lin[6*64*70];
    __shared__ float wl[64*26];

    for (int i = t; i < 64*25; i += 256) wl[(i/25)*26 + (i%25)] = dww[i];
    for (int i = t; i < 6*64*16; i += 256) {
        int q = i & 15, ch = (i >> 4) & 63, r = i >> 10;
        int hh = orow0 - 2 + r;
        u32 w0 = 0u, w1 = 0u;
        if (hh >= 0 && hh < H_) {
            const u32* src = (const u32*)(g1 + ((size_t)(b*CS+ch))*HW + hh*64 + q*4);
            w0 = src[0]; w1 = src[1];
        }
        u32* dst = (u32*)&lin[(r*64 + ch)*70 + 2 + q*4];
        dst[0] = w0; dst[1] = w1;
    }
    for (int i = t; i < 6*64; i += 256) {
        int ch = i & 63, r = i >> 6;
        *(u32*)&lin[(r*64 + ch)*70] = 0u;
        u32* e = (u32*)&lin[(r*64 + ch)*70 + 66];
        e[0] = 0u; e[1] = 0u;
    }
    __syncthreads();

    // out[:, :64] += c2*g1 for the 2 center rows (lin rows 2,3)
    for (int i = t; i < 2*64*16; i += 256) {
        int q = i & 15, ch = (i >> 4) & 63, r = i >> 10;
        const u16* src = &lin[((r+2)*64 + ch)*70 + 2 + q*4];
        float* op = out + ((size_t)(b*C_+ch))*HW + (size_t)(orow0+r)*64 + q*4;
        float4 ov = *(float4*)op;
        ov.x += c2*bf2f(src[0]); ov.y += c2*bf2f(src[1]);
        ov.z += c2*bf2f(src[2]); ov.w += c2*bf2f(src[3]);
        *(float4*)op = ov;
    }

    const int lane = t & 63, chl = lane & 15, cs = lane >> 4;
    const int wv = t >> 6, outrow = wv & 1, chhalf = wv >> 1;

    #pragma unroll
    for (int chi = 0; chi < 2; ++chi) {
        const int ch = chhalf*32 + chl + chi*16;
        const float* wch = &wl[ch*26];
        float accp[16];
        #pragma unroll
        for (int p = 0; p < 16; ++p) accp[p] = 0.f;
        #pragma unroll
        for (int kh = 0; kh < 5; ++kh) {
            const u16* src = &lin[((outrow + kh)*64 + ch)*70 + cs*16];
            float rb[20];
            #pragma unroll
            for (int k = 0; k < 10; ++k) {
                u32 u = *(const u32*)(src + 2*k);
                rb[2*k]   = __uint_as_float(u << 16);
                rb[2*k+1] = __uint_as_float(u & 0xFFFF0000u);
            }
            #pragma unroll
            for (int kw = 0; kw < 5; ++kw) {
                float wvv = wch[kh*5 + kw];
                #pragma unroll
                for (int p = 0; p < 16; ++p) accp[p] += rb[p+kw]*wvv;
            }
        }
        float s = gg[ch] * rsqrtf(vv[ch] + 1e-5f);
        float tt = bb[ch] - mm[ch]*s;
        float* op = out + ((size_t)(b*C_ + CS + ch))*HW + (size_t)(orow0+outrow)*64 + cs*16;
        #pragma unroll
        for (int q = 0; q < 4; ++q) {
            float4 ov = *(float4*)(op + q*4);
            ov.x += c2*silu_f(accp[q*4+0]*s + tt);
            ov.y += c2*silu_f(accp[q*4+1]*s + tt);
            ov.z += c2*silu_f(accp[q*4+2]*s + tt);
            ov.w += c2*silu_f(accp[q*4+3]*s + tt);
            *(float4*)(op + q*4) = ov;
        }
    }
}

extern "C" void kernel_launch(void* const* d_in, const int* in_sizes, int n_in,
                              void* d_out, int out_size, void* d_ws, size_t ws_size,
                              hipStream_t stream) {
    const float* x    = (const float*)d_in[0];
    const float* wts  = (const float*)d_in[1];
    const int*   idxs = (const int*)  d_in[2];
    const float* e0w  = (const float*)d_in[3];
    const float* e0g  = (const float*)d_in[4];
    const float* e0b  = (const float*)d_in[5];
    const float* e0m  = (const float*)d_in[6];
    const float* e0v  = (const float*)d_in[7];
    const float* e1dw = (const float*)d_in[8];
    const float* e1pw = (const float*)d_in[9];
    const float* e1g  = (const float*)d_in[10];
    const float* e1b  = (const float*)d_in[11];
    const float* e1m  = (const float*)d_in[12];
    const float* e1v  = (const float*)d_in[13];
    const float* e2aw = (const float*)d_in[14];
    const float* e2ag = (const float*)d_in[15];
    const float* e2ab = (const float*)d_in[16];
    const float* e2am = (const float*)d_in[17];
    const float* e2av = (const float*)d_in[18];
    const float* e2bw = (const float*)d_in[19];
    const float* e2bg = (const float*)d_in[20];
    const float* e2bb = (const float*)d_in[21];
    const float* e2bm = (const float*)d_in[22];
    const float* e2bv = (const float*)d_in[23];

    float* out = (float*)d_out;

    const size_t PLANE = (size_t)32*66*66*64;    // u16 per plane (17.8 MB)
    u16* xhA  = (u16*)d_ws;
    u16* xhB  = xhA + PLANE;
    u16* g1   = xhB + PLANE;                     // 16.8 MB
    u16* Wt0f = g1 + (size_t)8388608;
    u16* Wt2f = Wt0f + 73728;
    u16* Wt1f = Wt2f + 73728;

    k_prep<<<128, 256, 0, stream>>>(e0w, e2aw, e1pw, Wt0f, Wt2f, Wt1f);
    k_to_nhwc<<<dim3(64, B_), 256, 0, stream>>>(x, wts, idxs, xhA, xhB);
    k_conv<<<dim3(32, B_, 2), 256, 0, stream>>>(
        xhA, xhB, x, wts, idxs, Wt0f, Wt2f,
        e0g, e0b, e0m, e0v, e2ag, e2ab, e2am, e2av, out, g1);
    k_e1<<<dim3(32, B_), 256, 0, stream>>>(
        x, wts, idxs, e1dw, Wt1f, e1g, e1b, e1m, e1v, out);
    k_e2b<<<dim3(32, B_), 256, 0, stream>>>(
        g1, wts, idxs, e2bw, e2bg, e2bb, e2bm, e2bv, out);
}

// Round 12
// 104.662 us; speedup vs baseline: 1.2831x; 1.0310x over previous
//
#include <hip/hip_runtime.h>

#define B_  32
#define C_  128
#define CS  64
#define H_  64
#define W_  64
#define HW  (H_*W_)

typedef __attribute__((ext_vector_type(8))) short bf16x8_t;
typedef __attribute__((ext_vector_type(4))) float f32x4_t;
typedef unsigned short u16;
typedef unsigned int   u32;

__device__ __forceinline__ float silu_f(float v) { return v / (1.f + __expf(-v)); }

__device__ __forceinline__ u16 f2bf(float f) {
    u32 u = __float_as_uint(f);
    u = (u + 0x7FFFu + ((u >> 16) & 1u)) >> 16;   // RNE
    return (u16)u;
}
__device__ __forceinline__ float bf2f(u16 u) {
    return __uint_as_float(((u32)u) << 16);
}
__device__ __forceinline__ u32 pack2(float a, float b) {
    return (u32)f2bf(a) | ((u32)f2bf(b) << 16);
}

__device__ __forceinline__ void get_coeffs(const float* __restrict__ wts,
                                           const int* __restrict__ idxs, int b,
                                           float& c0, float& c1, float& c2, float& cid) {
    int   i0 = idxs[b*2+0], i1 = idxs[b*2+1];
    float w0 = wts[b*2+0],  w1 = wts[b*2+1];
    c0  = (i0==0?w0:0.f)   + (i1==0?w1:0.f);
    c1  = (i0==1?w0:0.f)   + (i1==1?w1:0.f);
    c2  = (i0==2?w0:0.f)   + (i1==2?w1:0.f);
    cid = (i0==3?0.1f:0.f) + (i1==3?0.1f:0.f);
}

// ---- weight prep: MFMA-fragment-ordered bf16 weights --------------------------
__global__ __launch_bounds__(256) void k_prep(
    const float* __restrict__ e0w, const float* __restrict__ e2aw, const float* __restrict__ e1pw,
    u16* __restrict__ Wt0f, u16* __restrict__ Wt2f, u16* __restrict__ Wt1f)
{
    const int i0 = blockIdx.x*256 + threadIdx.x, stride = gridDim.x*256;
    for (int i = i0; i < 73728; i += stride) {
        int j = i&7, lane = (i>>3)&63, cog = (i>>9)&7, kc = (i>>12)&1, tap = i>>13;
        int co = cog*16 + (lane&15), ci = kc*32 + (lane>>4)*8 + j;
        Wt0f[i] = f2bf(e0w[(size_t)(co*64 + ci)*9 + tap]);
    }
    for (int i = i0; i < 73728; i += stride) {
        int j = i&7, lane = (i>>3)&63, cog = (i>>9)&3, kc = (i>>11)&3, tap = i>>13;
        int co = cog*16 + (lane&15), ci = kc*32 + (lane>>4)*8 + j;
        Wt2f[i] = f2bf(e2aw[(size_t)(co*128 + ci)*9 + tap]);
    }
    for (int i = i0; i < 8192; i += stride) {
        int j = i&7, lane = (i>>3)&63, cog = (i>>9)&7, kc = (i>>12)&1;
        int co = cog*16 + (lane&15), ci = kc*32 + (lane>>4)*8 + j;
        Wt1f[i] = f2bf(e1pw[(size_t)co*64 + ci]);
    }
}

// ---- stage 4 padded rows x 66 cols x 64 ch from NCHW fp32 -> swizzled bf16 LDS -
// LDS element (p, ch) at byte (p*128 + ch*2) ^ ((p&7)<<4), p = r*66 + col.
__device__ __forceinline__ void stage_x(
    const float* __restrict__ xb,   // x + (b*C + ch0)*HW
    char* lin, int orow0, int t)
{
    #pragma unroll
    for (int k = 0; k < 8; ++k) {
        const int u = t + k*256;
        const int quad = u & 15, r = (u >> 4) & 3, cp = u >> 6;   // cp fixed per wave
        const int hh = orow0 - 1 + r;
        float4 v0, v1;
        if (hh >= 0 && hh < H_) {
            v0 = *(const float4*)(xb + (size_t)(2*cp)*HW + hh*64 + quad*4);
            v1 = *(const float4*)(xb + (size_t)(2*cp+1)*HW + hh*64 + quad*4);
        } else {
            v0.x = v0.y = v0.z = v0.w = 0.f;
            v1.x = v1.y = v1.z = v1.w = 0.f;
        }
        #pragma unroll
        for (int j = 0; j < 4; ++j) {
            const int p = r*66 + quad*4 + j + 1;
            const u32 a = ((u32)p*128 + (u32)cp*4) ^ (((u32)(p & 7)) << 4);
            *(u32*)(lin + a) = pack2((&v0.x)[j], (&v1.x)[j]);
        }
    }
    // border cols 0 and 65: 4 rows x 2 sides x 32 chpairs = 256 -> one per thread
    {
        const int cp = t & 31, side = (t >> 5) & 1, r = t >> 6;
        const int p = r*66 + side*65;
        const u32 a = ((u32)p*128 + (u32)cp*4) ^ (((u32)(p & 7)) << 4);
        *(u32*)(lin + a) = 0u;
    }
}

// ---- one K-pass over a staged 64-ch plane, asm A-loads + counted vmcnt --------
template<int NCF, int NPF, int TK, int COUT>
__device__ __forceinline__ void conv_pass(
    const char* lin, const u16* __restrict__ wb, int koff,
    int rbase, int pxbase, int l15, int kg,
    f32x4_t (&acc)[NCF][NPF])
{
    bf16x8_t A0[NCF], A1[NCF], A2[NCF];

    auto issueA = [&](int i, bf16x8_t (&dst)[NCF]) {
        const int tap = i >> 1, kcl = i & 1;
        const u16* wt = wb + (size_t)((tap*TK + koff + kcl)*(COUT/16))*512;
        #pragma unroll
        for (int cf = 0; cf < NCF; ++cf)
            asm volatile("global_load_dwordx4 %0, %1, off"
                         : "=v"(dst[cf]) : "v"(wt + ((size_t)cf << 9)));
    };
    auto ldsB = [&](int i, int pf) -> bf16x8_t {
        const int tap = i >> 1, kcl = i & 1;
        const int dh = tap / 3, dwp = tap % 3;
        const int p = (rbase + dh)*66 + pxbase + pf*16 + l15 + dwp;
        u32 a = (u32)p*128 + (u32)kcl*64 + (u32)kg*16;
        a ^= ((u32)(p & 7)) << 4;
        return *(const bf16x8_t*)(lin + a);
    };

    issueA(0, A0);
    issueA(1, A1);
    #pragma unroll
    for (int i = 0; i < 18; ++i) {
        if (i + 2 < 18) {
            const int s = (i + 2) % 3;
            if (s == 0)      issueA(i + 2, A0);
            else if (s == 1) issueA(i + 2, A1);
            else             issueA(i + 2, A2);
        }
        if (i < 16)       asm volatile("s_waitcnt vmcnt(8)" ::: "memory");
        else if (i == 16) asm volatile("s_waitcnt vmcnt(4)" ::: "memory");
        else              asm volatile("s_waitcnt vmcnt(0)" ::: "memory");
        __builtin_amdgcn_sched_barrier(0);
        bf16x8_t* ac = (i % 3 == 0) ? A0 : ((i % 3 == 1) ? A1 : A2);
        #pragma unroll
        for (int pf = 0; pf < NPF; ++pf) {
            bf16x8_t bfr = ldsB(i, pf);
            #pragma unroll
            for (int cf = 0; cf < NCF; ++cf)
                acc[cf][pf] = __builtin_amdgcn_mfma_f32_16x16x32_bf16(ac[cf], bfr, acc[cf][pf], 0, 0, 0);
        }
    }
}

// ---- merged conv kernel: grid (32 bands, B, 2). z=0 e0, z=1 e2a. --------------
// Direct NCHW staging (no xh intermediate). LDS 33.8 KB.
__global__ __launch_bounds__(256, 3) void k_conv(
    const float* __restrict__ x,
    const float* __restrict__ wts, const int* __restrict__ idxs,
    const u16* __restrict__ Wt0f, const u16* __restrict__ Wt2f,
    const float* __restrict__ e0g, const float* __restrict__ e0b,
    const float* __restrict__ e0m, const float* __restrict__ e0v,
    const float* __restrict__ e2ag, const float* __restrict__ e2ab,
    const float* __restrict__ e2am, const float* __restrict__ e2av,
    float* __restrict__ out, u16* __restrict__ g1)
{
    __shared__ char lin[33792];
    const int b = blockIdx.y, orow0 = blockIdx.x*2, t = threadIdx.x;
    float c0, c1, c2, cid;
    get_coeffs(wts, idxs, b, c0, c1, c2, cid);

    const int lane = t & 63, l15 = lane & 15, kg = lane >> 4, wv = t >> 6;
    const float* xb = x + (size_t)b*C_*HW;

    if (blockIdx.z == 0) {
        if (c0 == 0.f) {   // identity-only init of these 2 rows (all 128 ch)
            for (int i = t; i < 4096; i += 256) {
                int ch = i >> 5, q = i & 31;
                size_t o = ((size_t)(b*C_+ch))*HW + (size_t)orow0*64 + q*4;
                float4 ov;
                if (cid != 0.f) {
                    float4 xv = *(const float4*)(x + o);
                    ov.x = cid*xv.x; ov.y = cid*xv.y; ov.z = cid*xv.z; ov.w = cid*xv.w;
                } else { ov.x = ov.y = ov.z = ov.w = 0.f; }
                *(float4*)(out + o) = ov;
            }
            return;
        }
        stage_x(xb, lin, orow0, t);
        __syncthreads();

        const int cw = wv >> 1, rw = wv & 1;
        const int cobase = cw*64;
        f32x4_t acc[4][4];
        #pragma unroll
        for (int cf = 0; cf < 4; ++cf)
            #pragma unroll
            for (int pf = 0; pf < 4; ++pf)
                acc[cf][pf] = (f32x4_t){0.f, 0.f, 0.f, 0.f};

        const u16* wb = Wt0f + (size_t)(cobase >> 4)*512 + (size_t)lane*8;
        conv_pass<4, 4, 2, 128>(lin, wb, 0, rw, 0, l15, kg, acc);

        #pragma unroll
        for (int cf = 0; cf < 4; ++cf) {
            float sarr[4], tarr[4];
            #pragma unroll
            for (int r = 0; r < 4; ++r) {
                int co = cobase + cf*16 + kg*4 + r;
                float s = e0g[co] * rsqrtf(e0v[co] + 1e-5f);
                sarr[r] = s; tarr[r] = e0b[co] - e0m[co]*s;
            }
            #pragma unroll
            for (int pf = 0; pf < 4; ++pf) {
                size_t rowoff = (size_t)(orow0 + rw)*64 + pf*16 + l15;
                #pragma unroll
                for (int r = 0; r < 4; ++r) {
                    int co = cobase + cf*16 + kg*4 + r;
                    float v = silu_f(acc[cf][pf][r]*sarr[r] + tarr[r]);
                    size_t o = ((size_t)(b*C_+co))*HW + rowoff;
                    float idv = (cid != 0.f) ? cid*x[o] : 0.f;
                    out[o] = c0*v + idv;
                }
            }
        }
    } else {
        if (c2 == 0.f) return;

        const int rw = wv >> 1, pw = wv & 1;
        const int pxbase = pw*32;
        f32x4_t acc[4][2];
        #pragma unroll
        for (int cf = 0; cf < 4; ++cf)
            #pragma unroll
            for (int pf = 0; pf < 2; ++pf)
                acc[cf][pf] = (f32x4_t){0.f, 0.f, 0.f, 0.f};

        const u16* wb = Wt2f + (size_t)lane*8;

        stage_x(xb, lin, orow0, t);
        __syncthreads();
        conv_pass<4, 2, 4, 64>(lin, wb, 0, rw, pxbase, l15, kg, acc);
        __syncthreads();
        stage_x(xb + (size_t)CS*HW, lin, orow0, t);
        __syncthreads();
        conv_pass<4, 2, 4, 64>(lin, wb, 2, rw, pxbase, l15, kg, acc);

        #pragma unroll
        for (int cf = 0; cf < 4; ++cf) {
            float sarr[4], tarr[4];
            #pragma unroll
            for (int r = 0; r < 4; ++r) {
                int co = cf*16 + kg*4 + r;
                float s = e2ag[co] * rsqrtf(e2av[co] + 1e-5f);
                sarr[r] = s; tarr[r] = e2ab[co] - e2am[co]*s;
            }
            #pragma unroll
            for (int pf = 0; pf < 2; ++pf) {
                size_t rowoff = (size_t)(orow0 + rw)*64 + pxbase + pf*16 + l15;
                #pragma unroll
                for (int r = 0; r < 4; ++r) {
                    int co = cf*16 + kg*4 + r;
                    float v = silu_f(acc[cf][pf][r]*sarr[r] + tarr[r]);
                    g1[((size_t)(b*CS+co))*HW + rowoff] = f2bf(v);
                }
            }
        }
    }
}

// ---- fused e1: dw5x5(x_ir) in LDS -> pw1x1 MFMA -> BN/SiLU -> out += c1*e1 ----
__global__ __launch_bounds__(256) void k_e1(
    const float* __restrict__ x, const float* __restrict__ wts, const int* __restrict__ idxs,
    const float* __restrict__ dww, const u16* __restrict__ Wt1f,
    const float* __restrict__ gg, const float* __restrict__ bb,
    const float* __restrict__ mm, const float* __restrict__ vv,
    float* __restrict__ out)
{
    const int b = blockIdx.y, band = blockIdx.x, t = threadIdx.x;
    const int orow0 = band*2;

    float c0, c1, c2, cid;
    get_coeffs(wts, idxs, b, c0, c1, c2, cid);
    if (c1 == 0.f) return;

    __shared__ u16  lin[6*64*70];   // [row6][ch64][col70] cols -2..65 (+pad), bf16
    __shared__ u16  lout[128*72];   // [px128][ci72pad] bf16
    __shared__ float wl[64*26];

    for (int i = t; i < 64*25; i += 256) wl[(i/25)*26 + (i%25)] = dww[i];
    for (int i = t; i < 6*64*16; i += 256) {
        int q = i & 15, ch = (i >> 4) & 63, r = i >> 10;
        int hh = orow0 - 2 + r;
        u32 w0 = 0u, w1 = 0u;
        if (hh >= 0 && hh < H_) {
            float4 v = *(const float4*)(x + ((size_t)(b*C_ + CS + ch))*HW + hh*64 + q*4);
            w0 = pack2(v.x, v.y); w1 = pack2(v.z, v.w);
        }
        u32* dst = (u32*)&lin[(r*64 + ch)*70 + 2 + q*4];
        dst[0] = w0; dst[1] = w1;
    }
    for (int i = t; i < 6*64; i += 256) {
        int ch = i & 63, r = i >> 6;
        *(u32*)&lin[(r*64 + ch)*70]      = 0u;
        u32* e = (u32*)&lin[(r*64 + ch)*70 + 66];
        e[0] = 0u; e[1] = 0u;
    }
    __syncthreads();

    const int lane = t & 63, chl = lane & 15, cs = lane >> 4;
    const int wv = t >> 6, outrow = wv & 1, chhalf = wv >> 1;

    #pragma unroll
    for (int chi = 0; chi < 2; ++chi) {
        const int ch = chhalf*32 + chl + chi*16;
        const float* wch = &wl[ch*26];
        float accp[16];
        #pragma unroll
        for (int p = 0; p < 16; ++p) accp[p] = 0.f;
        #pragma unroll
        for (int kh = 0; kh < 5; ++kh) {
            const u16* src = &lin[((outrow + kh)*64 + ch)*70 + cs*16];
            float rb[20];
            #pragma unroll
            for (int k = 0; k < 10; ++k) {
                u32 u = *(const u32*)(src + 2*k);
                rb[2*k]   = __uint_as_float(u << 16);
                rb[2*k+1] = __uint_as_float(u & 0xFFFF0000u);
            }
            #pragma unroll
            for (int kw = 0; kw < 5; ++kw) {
                float wvv = wch[kh*5 + kw];
                #pragma unroll
                for (int p = 0; p < 16; ++p) accp[p] += rb[p+kw]*wvv;
            }
        }
        const int px0 = outrow*64 + cs*16;
        #pragma unroll
        for (int p = 0; p < 16; ++p) lout[(px0+p)*72 + ch] = f2bf(accp[p]);
    }
    __syncthreads();

    const int l15 = lane & 15, kg = lane >> 4;
    const int cw = wv >> 1, pwv = wv & 1;
    f32x4_t acc[4][4];
    #pragma unroll
    for (int cf = 0; cf < 4; ++cf)
        #pragma unroll
        for (int pf = 0; pf < 4; ++pf)
            acc[cf][pf] = (f32x4_t){0.f, 0.f, 0.f, 0.f};

    #pragma unroll
    for (int kc = 0; kc < 2; ++kc) {
        const u16* wt = Wt1f + (((size_t)(kc*8 + cw*4)) << 9) + lane*8;
        bf16x8_t af[4];
        #pragma unroll
        for (int cf = 0; cf < 4; ++cf) af[cf] = *(const bf16x8_t*)(wt + (cf << 9));
        const int k0 = kc*32 + kg*8;
        #pragma unroll
        for (int pf = 0; pf < 4; ++pf) {
            bf16x8_t bfr = *(const bf16x8_t*)&lout[(pwv*64 + pf*16 + l15)*72 + k0];
            #pragma unroll
            for (int cf = 0; cf < 4; ++cf)
                acc[cf][pf] = __builtin_amdgcn_mfma_f32_16x16x32_bf16(af[cf], bfr, acc[cf][pf], 0, 0, 0);
        }
    }

    #pragma unroll
    for (int cf = 0; cf < 4; ++cf) {
        float sarr[4], tarr[4];
        #pragma unroll
        for (int r = 0; r < 4; ++r) {
            int co = cw*64 + cf*16 + kg*4 + r;
            float s = gg[co] * rsqrtf(vv[co] + 1e-5f);
            sarr[r] = s; tarr[r] = bb[co] - mm[co]*s;
        }
        #pragma unroll
        for (int pf = 0; pf < 4; ++pf) {
            int px = pwv*64 + pf*16 + l15;
            size_t rowoff = (size_t)(orow0 + (px>>6))*64 + (px&63);
            #pragma unroll
            for (int r = 0; r < 4; ++r) {
                int co = cw*64 + cf*16 + kg*4 + r;
                float v = silu_f(acc[cf][pf][r]*sarr[r] + tarr[r]);
                out[((size_t)(b*C_+co))*HW + rowoff] += c1*v;
            }
        }
    }
}

// ---- e2b: out[:, :64] += c2*g1 ; out[:, 64:] += c2*silu(bn(dw5x5(g1))) --------
__global__ __launch_bounds__(256) void k_e2b(
    const u16* __restrict__ g1, const float* __restrict__ wts, const int* __restrict__ idxs,
    const float* __restrict__ dww, const float* __restrict__ gg, const float* __restrict__ bb,
    const float* __restrict__ mm, const float* __restrict__ vv, float* __restrict__ out)
{
    const int b = blockIdx.y, band = blockIdx.x, t = threadIdx.x;
    const int orow0 = band*2;

    float c0, c1, c2, cid;
    get_coeffs(wts, idxs, b, c0, c1, c2, cid);
    if (c2 == 0.f) return;

    __shared__ u16  lin[6*64*70];
    __shared__ float wl[64*26];

    for (int i = t; i < 64*25; i += 256) wl[(i/25)*26 + (i%25)] = dww[i];
    for (int i = t; i < 6*64*16; i += 256) {
        int q = i & 15, ch = (i >> 4) & 63, r = i >> 10;
        int hh = orow0 - 2 + r;
        u32 w0 = 0u, w1 = 0u;
        if (hh >= 0 && hh < H_) {
            const u32* src = (const u32*)(g1 + ((size_t)(b*CS+ch))*HW + hh*64 + q*4);
            w0 = src[0]; w1 = src[1];
        }
        u32* dst = (u32*)&lin[(r*64 + ch)*70 + 2 + q*4];
        dst[0] = w0; dst[1] = w1;
    }
    for (int i = t; i < 6*64; i += 256) {
        int ch = i & 63, r = i >> 6;
        *(u32*)&lin[(r*64 + ch)*70] = 0u;
        u32* e = (u32*)&lin[(r*64 + ch)*70 + 66];
        e[0] = 0u; e[1] = 0u;
    }
    __syncthreads();

    // out[:, :64] += c2*g1 for the 2 center rows (lin rows 2,3)
    for (int i = t; i < 2*64*16; i += 256) {
        int q = i & 15, ch = (i >> 4) & 63, r = i >> 10;
        const u16* src = &lin[((r+2)*64 + ch)*70 + 2 + q*4];
        float* op = out + ((size_t)(b*C_+ch))*HW + (size_t)(orow0+r)*64 + q*4;
        float4 ov = *(float4*)op;
        ov.x += c2*bf2f(src[0]); ov.y += c2*bf2f(src[1]);
        ov.z += c2*bf2f(src[2]); ov.w += c2*bf2f(src[3]);
        *(float4*)op = ov;
    }

    const int lane = t & 63, chl = lane & 15, cs = lane >> 4;
    const int wv = t >> 6, outrow = wv & 1, chhalf = wv >> 1;

    #pragma unroll
    for (int chi = 0; chi < 2; ++chi) {
        const int ch = chhalf*32 + chl + chi*16;
        const float* wch = &wl[ch*26];
        float accp[16];
        #pragma unroll
        for (int p = 0; p < 16; ++p) accp[p] = 0.f;
        #pragma unroll
        for (int kh = 0; kh < 5; ++kh) {
            const u16* src = &lin[((outrow + kh)*64 + ch)*70 + cs*16];
            float rb[20];
            #pragma unroll
            for (int k = 0; k < 10; ++k) {
                u32 u = *(const u32*)(src + 2*k);
                rb[2*k]   = __uint_as_float(u << 16);
                rb[2*k+1] = __uint_as_float(u & 0xFFFF0000u);
            }
            #pragma unroll
            for (int kw = 0; kw < 5; ++kw) {
                float wvv = wch[kh*5 + kw];
                #pragma unroll
                for (int p = 0; p < 16; ++p) accp[p] += rb[p+kw]*wvv;
            }
        }
        float s = gg[ch] * rsqrtf(vv[ch] + 1e-5f);
        float tt = bb[ch] - mm[ch]*s;
        float* op = out + ((size_t)(b*C_ + CS + ch))*HW + (size_t)(orow0+outrow)*64 + cs*16;
        #pragma unroll
        for (int q = 0; q < 4; ++q) {
            float4 ov = *(float4*)(op + q*4);
            ov.x += c2*silu_f(accp[q*4+0]*s + tt);
            ov.y += c2*silu_f(accp[q*4+1]*s + tt);
            ov.z += c2*silu_f(accp[q*4+2]*s + tt);
            ov.w += c2*silu_f(accp[q*4+3]*s + tt);
            *(float4*)(op + q*4) = ov;
        }
    }
}

extern "C" void kernel_launch(void* const* d_in, const int* in_sizes, int n_in,
                              void* d_out, int out_size, void* d_ws, size_t ws_size,
                              hipStream_t stream) {
    const float* x    = (const float*)d_in[0];
    const float* wts  = (const float*)d_in[1];
    const int*   idxs = (const int*)  d_in[2];
    const float* e0w  = (const float*)d_in[3];
    const float* e0g  = (const float*)d_in[4];
    const float* e0b  = (const float*)d_in[5];
    const float* e0m  = (const float*)d_in[6];
    const float* e0v  = (const float*)d_in[7];
    const float* e1dw = (const float*)d_in[8];
    const float* e1pw = (const float*)d_in[9];
    const float* e1g  = (const float*)d_in[10];
    const float* e1b  = (const float*)d_in[11];
    const float* e1m  = (const float*)d_in[12];
    const float* e1v  = (const float*)d_in[13];
    const float* e2aw = (const float*)d_in[14];
    const float* e2ag = (const float*)d_in[15];
    const float* e2ab = (const float*)d_in[16];
    const float* e2am = (const float*)d_in[17];
    const float* e2av = (const float*)d_in[18];
    const float* e2bw = (const float*)d_in[19];
    const float* e2bg = (const float*)d_in[20];
    const float* e2bb = (const float*)d_in[21];
    const float* e2bm = (const float*)d_in[22];
    const float* e2bv = (const float*)d_in[23];

    float* out = (float*)d_out;

    u16* g1   = (u16*)d_ws;                      // 16.8 MB
    u16* Wt0f = g1 + (size_t)8388608;
    u16* Wt2f = Wt0f + 73728;
    u16* Wt1f = Wt2f + 73728;

    k_prep<<<128, 256, 0, stream>>>(e0w, e2aw, e1pw, Wt0f, Wt2f, Wt1f);
    k_conv<<<dim3(32, B_, 2), 256, 0, stream>>>(
        x, wts, idxs, Wt0f, Wt2f,
        e0g, e0b, e0m, e0v, e2ag, e2ab, e2am, e2av, out, g1);
    k_e1<<<dim3(32, B_), 256, 0, stream>>>(
        x, wts, idxs, e1dw, Wt1f, e1g, e1b, e1m, e1v, out);
    k_e2b<<<dim3(32, B_), 256, 0, stream>>>(
        g1, wts, idxs, e2bw, e2bg, e2bb, e2bm, e2bv, out);
}

// Round 13
// 97.081 us; speedup vs baseline: 1.3832x; 1.0781x over previous
//
#include <hip/hip_runtime.h>

#define B_  32
#define C_  128
#define CS  64
#define H_  64
#define W_  64
#define HW  (H_*W_)

typedef __attribute__((ext_vector_type(8))) short bf16x8_t;
typedef __attribute__((ext_vector_type(4))) float f32x4_t;
typedef unsigned short u16;
typedef unsigned int   u32;

__device__ __forceinline__ float silu_f(float v) { return v / (1.f + __expf(-v)); }

__device__ __forceinline__ u16 f2bf(float f) {
    u32 u = __float_as_uint(f);
    u = (u + 0x7FFFu + ((u >> 16) & 1u)) >> 16;   // RNE
    return (u16)u;
}
__device__ __forceinline__ float bf2f(u16 u) {
    return __uint_as_float(((u32)u) << 16);
}
// one-instruction RNE pack of 2 floats -> 2 bf16 (lo = a, hi = b)
__device__ __forceinline__ u32 cvtpk(float a, float b) {
    u32 r;
    asm("v_cvt_pk_bf16_f32 %0, %1, %2" : "=v"(r) : "v"(a), "v"(b));
    return r;
}

__device__ __forceinline__ void get_coeffs(const float* __restrict__ wts,
                                           const int* __restrict__ idxs, int b,
                                           float& c0, float& c1, float& c2, float& cid) {
    int   i0 = idxs[b*2+0], i1 = idxs[b*2+1];
    float w0 = wts[b*2+0],  w1 = wts[b*2+1];
    c0  = (i0==0?w0:0.f)   + (i1==0?w1:0.f);
    c1  = (i0==1?w0:0.f)   + (i1==1?w1:0.f);
    c2  = (i0==2?w0:0.f)   + (i1==2?w1:0.f);
    cid = (i0==3?0.1f:0.f) + (i1==3?0.1f:0.f);
}

// ---- weight prep: MFMA-fragment-ordered bf16 weights --------------------------
__global__ __launch_bounds__(256) void k_prep(
    const float* __restrict__ e0w, const float* __restrict__ e2aw, const float* __restrict__ e1pw,
    u16* __restrict__ Wt0f, u16* __restrict__ Wt2f, u16* __restrict__ Wt1f)
{
    const int i0 = blockIdx.x*256 + threadIdx.x, stride = gridDim.x*256;
    for (int i = i0; i < 73728; i += stride) {
        int j = i&7, lane = (i>>3)&63, cog = (i>>9)&7, kc = (i>>12)&1, tap = i>>13;
        int co = cog*16 + (lane&15), ci = kc*32 + (lane>>4)*8 + j;
        Wt0f[i] = f2bf(e0w[(size_t)(co*64 + ci)*9 + tap]);
    }
    for (int i = i0; i < 73728; i += stride) {
        int j = i&7, lane = (i>>3)&63, cog = (i>>9)&3, kc = (i>>11)&3, tap = i>>13;
        int co = cog*16 + (lane&15), ci = kc*32 + (lane>>4)*8 + j;
        Wt2f[i] = f2bf(e2aw[(size_t)(co*128 + ci)*9 + tap]);
    }
    for (int i = i0; i < 8192; i += stride) {
        int j = i&7, lane = (i>>3)&63, cog = (i>>9)&7, kc = (i>>12)&1;
        int co = cog*16 + (lane&15), ci = kc*32 + (lane>>4)*8 + j;
        Wt1f[i] = f2bf(e1pw[(size_t)co*64 + ci]);
    }
}

// ---- stage 4 padded rows x 66 cols x 64 ch from NCHW fp32 -> swizzled bf16 LDS -
// All 16 global loads issued up front (asm), single vmcnt(0), then convert+write.
__device__ __forceinline__ void stage_x(
    const float* __restrict__ xb,   // x + (b*C + ch0)*HW
    char* lin, int orow0, int t)
{
    f32x4_t V0[8], V1[8];
    #pragma unroll
    for (int k = 0; k < 8; ++k) {
        const int u = t + k*256;
        const int quad = u & 15, r = (u >> 4) & 3, cp = u >> 6;
        const int hh = orow0 - 1 + r;
        const int hcl = (hh < 0) ? 0 : ((hh > 63) ? 63 : hh);
        const float* p0 = xb + (size_t)(2*cp)*HW + hcl*64 + quad*4;
        asm volatile("global_load_dwordx4 %0, %1, off" : "=v"(V0[k]) : "v"(p0));
        asm volatile("global_load_dwordx4 %0, %1, off" : "=v"(V1[k]) : "v"(p0 + HW));
    }
    asm volatile("s_waitcnt vmcnt(0)" ::: "memory");
    __builtin_amdgcn_sched_barrier(0);
    #pragma unroll
    for (int k = 0; k < 8; ++k) {
        const int u = t + k*256;
        const int quad = u & 15, r = (u >> 4) & 3, cp = u >> 6;
        const int hh = orow0 - 1 + r;
        const bool ok = (hh >= 0 && hh < H_);
        #pragma unroll
        for (int j = 0; j < 4; ++j) {
            const int p = r*66 + quad*4 + j + 1;
            const u32 a = ((u32)p*128 + (u32)cp*4) ^ (((u32)(p & 7)) << 4);
            float f0 = ok ? V0[k][j] : 0.f;
            float f1 = ok ? V1[k][j] : 0.f;
            *(u32*)(lin + a) = cvtpk(f0, f1);
        }
    }
    // border cols 0 and 65: 4 rows x 2 sides x 32 chpairs = 256 -> one per thread
    {
        const int cp = t & 31, side = (t >> 5) & 1, r = t >> 6;
        const int p = r*66 + side*65;
        const u32 a = ((u32)p*128 + (u32)cp*4) ^ (((u32)(p & 7)) << 4);
        *(u32*)(lin + a) = 0u;
    }
}

// ---- one K-pass over a staged 64-ch plane, asm A-loads + counted vmcnt --------
template<int NCF, int NPF, int TK, int COUT>
__device__ __forceinline__ void conv_pass(
    const char* lin, const u16* __restrict__ wb, int koff,
    int rbase, int pxbase, int l15, int kg,
    f32x4_t (&acc)[NCF][NPF])
{
    bf16x8_t A0[NCF], A1[NCF], A2[NCF];

    auto issueA = [&](int i, bf16x8_t (&dst)[NCF]) {
        const int tap = i >> 1, kcl = i & 1;
        const u16* wt = wb + (size_t)((tap*TK + koff + kcl)*(COUT/16))*512;
        #pragma unroll
        for (int cf = 0; cf < NCF; ++cf)
            asm volatile("global_load_dwordx4 %0, %1, off"
                         : "=v"(dst[cf]) : "v"(wt + ((size_t)cf << 9)));
    };
    auto ldsB = [&](int i, int pf) -> bf16x8_t {
        const int tap = i >> 1, kcl = i & 1;
        const int dh = tap / 3, dwp = tap % 3;
        const int p = (rbase + dh)*66 + pxbase + pf*16 + l15 + dwp;
        u32 a = (u32)p*128 + (u32)kcl*64 + (u32)kg*16;
        a ^= ((u32)(p & 7)) << 4;
        return *(const bf16x8_t*)(lin + a);
    };

    issueA(0, A0);
    issueA(1, A1);
    #pragma unroll
    for (int i = 0; i < 18; ++i) {
        if (i + 2 < 18) {
            const int s = (i + 2) % 3;
            if (s == 0)      issueA(i + 2, A0);
            else if (s == 1) issueA(i + 2, A1);
            else             issueA(i + 2, A2);
        }
        if (i < 16)       asm volatile("s_waitcnt vmcnt(8)" ::: "memory");
        else if (i == 16) asm volatile("s_waitcnt vmcnt(4)" ::: "memory");
        else              asm volatile("s_waitcnt vmcnt(0)" ::: "memory");
        __builtin_amdgcn_sched_barrier(0);
        bf16x8_t* ac = (i % 3 == 0) ? A0 : ((i % 3 == 1) ? A1 : A2);
        #pragma unroll
        for (int pf = 0; pf < NPF; ++pf) {
            bf16x8_t bfr = ldsB(i, pf);
            #pragma unroll
            for (int cf = 0; cf < NCF; ++cf)
                acc[cf][pf] = __builtin_amdgcn_mfma_f32_16x16x32_bf16(ac[cf], bfr, acc[cf][pf], 0, 0, 0);
        }
    }
}

// ---- merged conv kernel: grid (32 bands, B, 2). z=0 e0, z=1 e2a. --------------
__global__ __launch_bounds__(256, 3) void k_conv(
    const float* __restrict__ x,
    const float* __restrict__ wts, const int* __restrict__ idxs,
    const u16* __restrict__ Wt0f, const u16* __restrict__ Wt2f,
    const float* __restrict__ e0g, const float* __restrict__ e0b,
    const float* __restrict__ e0m, const float* __restrict__ e0v,
    const float* __restrict__ e2ag, const float* __restrict__ e2ab,
    const float* __restrict__ e2am, const float* __restrict__ e2av,
    float* __restrict__ out, u16* __restrict__ g1)
{
    __shared__ char lin[33792];
    const int b = blockIdx.y, orow0 = blockIdx.x*2, t = threadIdx.x;
    float c0, c1, c2, cid;
    get_coeffs(wts, idxs, b, c0, c1, c2, cid);

    const int lane = t & 63, l15 = lane & 15, kg = lane >> 4, wv = t >> 6;
    const float* xb = x + (size_t)b*C_*HW;

    if (blockIdx.z == 0) {
        if (c0 == 0.f) {   // identity-only init of these 2 rows (all 128 ch)
            for (int i = t; i < 4096; i += 256) {
                int ch = i >> 5, q = i & 31;
                size_t o = ((size_t)(b*C_+ch))*HW + (size_t)orow0*64 + q*4;
                float4 ov;
                if (cid != 0.f) {
                    float4 xv = *(const float4*)(x + o);
                    ov.x = cid*xv.x; ov.y = cid*xv.y; ov.z = cid*xv.z; ov.w = cid*xv.w;
                } else { ov.x = ov.y = ov.z = ov.w = 0.f; }
                *(float4*)(out + o) = ov;
            }
            return;
        }
        stage_x(xb, lin, orow0, t);
        __syncthreads();

        const int cw = wv >> 1, rw = wv & 1;
        const int cobase = cw*64;
        f32x4_t acc[4][4];
        #pragma unroll
        for (int cf = 0; cf < 4; ++cf)
            #pragma unroll
            for (int pf = 0; pf < 4; ++pf)
                acc[cf][pf] = (f32x4_t){0.f, 0.f, 0.f, 0.f};

        const u16* wb = Wt0f + (size_t)(cobase >> 4)*512 + (size_t)lane*8;
        conv_pass<4, 4, 2, 128>(lin, wb, 0, rw, 0, l15, kg, acc);

        #pragma unroll
        for (int cf = 0; cf < 4; ++cf) {
            float sarr[4], tarr[4];
            #pragma unroll
            for (int r = 0; r < 4; ++r) {
                int co = cobase + cf*16 + kg*4 + r;
                float s = e0g[co] * rsqrtf(e0v[co] + 1e-5f);
                sarr[r] = s; tarr[r] = e0b[co] - e0m[co]*s;
            }
            #pragma unroll
            for (int pf = 0; pf < 4; ++pf) {
                size_t rowoff = (size_t)(orow0 + rw)*64 + pf*16 + l15;
                #pragma unroll
                for (int r = 0; r < 4; ++r) {
                    int co = cobase + cf*16 + kg*4 + r;
                    float v = silu_f(acc[cf][pf][r]*sarr[r] + tarr[r]);
                    size_t o = ((size_t)(b*C_+co))*HW + rowoff;
                    float idv = (cid != 0.f) ? cid*x[o] : 0.f;
                    out[o] = c0*v + idv;
                }
            }
        }
    } else {
        if (c2 == 0.f) return;

        const int rw = wv >> 1, pw = wv & 1;
        const int pxbase = pw*32;
        f32x4_t acc[4][2];
        #pragma unroll
        for (int cf = 0; cf < 4; ++cf)
            #pragma unroll
            for (int pf = 0; pf < 2; ++pf)
                acc[cf][pf] = (f32x4_t){0.f, 0.f, 0.f, 0.f};

        const u16* wb = Wt2f + (size_t)lane*8;

        stage_x(xb, lin, orow0, t);
        __syncthreads();
        conv_pass<4, 2, 4, 64>(lin, wb, 0, rw, pxbase, l15, kg, acc);
        __syncthreads();
        stage_x(xb + (size_t)CS*HW, lin, orow0, t);
        __syncthreads();
        conv_pass<4, 2, 4, 64>(lin, wb, 2, rw, pxbase, l15, kg, acc);

        #pragma unroll
        for (int cf = 0; cf < 4; ++cf) {
            float sarr[4], tarr[4];
            #pragma unroll
            for (int r = 0; r < 4; ++r) {
                int co = cf*16 + kg*4 + r;
                float s = e2ag[co] * rsqrtf(e2av[co] + 1e-5f);
                sarr[r] = s; tarr[r] = e2ab[co] - e2am[co]*s;
            }
            #pragma unroll
            for (int pf = 0; pf < 2; ++pf) {
                size_t rowoff = (size_t)(orow0 + rw)*64 + pxbase + pf*16 + l15;
                #pragma unroll
                for (int r = 0; r < 4; ++r) {
                    int co = cf*16 + kg*4 + r;
                    float v = silu_f(acc[cf][pf][r]*sarr[r] + tarr[r]);
                    g1[((size_t)(b*CS+co))*HW + rowoff] = f2bf(v);
                }
            }
        }
    }
}

// ---- tail: e1 (dw5x5+pw+BN/SiLU, out += c1*e1) then e2b (out += c2*[g1,g2]) ---
// One block per (band, b); sequential phases share LDS; no cross-block races.
__global__ __launch_bounds__(256) void k_tail(
    const float* __restrict__ x, const u16* __restrict__ g1,
    const float* __restrict__ wts, const int* __restrict__ idxs,
    const float* __restrict__ e1dw, const u16* __restrict__ Wt1f,
    const float* __restrict__ e1g, const float* __restrict__ e1b,
    const float* __restrict__ e1m, const float* __restrict__ e1v,
    const float* __restrict__ e2bw,
    const float* __restrict__ e2bg, const float* __restrict__ e2bb,
    const float* __restrict__ e2bm, const float* __restrict__ e2bv,
    float* __restrict__ out)
{
    const int b = blockIdx.y, band = blockIdx.x, t = threadIdx.x;
    const int orow0 = band*2;

    float c0, c1, c2, cid;
    get_coeffs(wts, idxs, b, c0, c1, c2, cid);
    if (c1 == 0.f && c2 == 0.f) return;

    __shared__ u16  lin[6*64*70];   // [row6][ch64][col70], bf16
    __shared__ u16  lout[128*72];   // [px128][ci72pad] bf16 (e1 only)
    __shared__ float wl[64*26];

    const int lane = t & 63, chl = lane & 15, cs = lane >> 4;
    const int wv = t >> 6, outrow = wv & 1, chhalf = wv >> 1;
    const int l15 = lane & 15, kg = lane >> 4;

    if (c1 != 0.f) {
        // ---- stage x_ir ----
        for (int i = t; i < 64*25; i += 256) wl[(i/25)*26 + (i%25)] = e1dw[i];
        for (int i = t; i < 6*64*16; i += 256) {
            int q = i & 15, ch = (i >> 4) & 63, r = i >> 10;
            int hh = orow0 - 2 + r;
            u32 w0 = 0u, w1 = 0u;
            if (hh >= 0 && hh < H_) {
                float4 v = *(const float4*)(x + ((size_t)(b*C_ + CS + ch))*HW + hh*64 + q*4);
                w0 = cvtpk(v.x, v.y); w1 = cvtpk(v.z, v.w);
            }
            u32* dst = (u32*)&lin[(r*64 + ch)*70 + 2 + q*4];
            dst[0] = w0; dst[1] = w1;
        }
        for (int i = t; i < 6*64; i += 256) {
            int ch = i & 63, r = i >> 6;
            *(u32*)&lin[(r*64 + ch)*70]      = 0u;
            u32* e = (u32*)&lin[(r*64 + ch)*70 + 66];
            e[0] = 0u; e[1] = 0u;
        }
        __syncthreads();

        // ---- dw 5x5 -> lout ----
        #pragma unroll
        for (int chi = 0; chi < 2; ++chi) {
            const int ch = chhalf*32 + chl + chi*16;
            const float* wch = &wl[ch*26];
            float accp[16];
            #pragma unroll
            for (int p = 0; p < 16; ++p) accp[p] = 0.f;
            #pragma unroll
            for (int kh = 0; kh < 5; ++kh) {
                const u16* src = &lin[((outrow + kh)*64 + ch)*70 + cs*16];
                float rb[20];
                #pragma unroll
                for (int k = 0; k < 10; ++k) {
                    u32 u = *(const u32*)(src + 2*k);
                    rb[2*k]   = __uint_as_float(u << 16);
                    rb[2*k+1] = __uint_as_float(u & 0xFFFF0000u);
                }
                #pragma unroll
                for (int kw = 0; kw < 5; ++kw) {
                    float wvv = wch[kh*5 + kw];
                    #pragma unroll
                    for (int p = 0; p < 16; ++p) accp[p] += rb[p+kw]*wvv;
                }
            }
            const int px0 = outrow*64 + cs*16;
            #pragma unroll
            for (int p = 0; p < 16; ++p) lout[(px0+p)*72 + ch] = f2bf(accp[p]);
        }
        __syncthreads();

        // ---- pw MFMA + BN/SiLU + out += c1*e1 ----
        const int cw = wv >> 1, pwv = wv & 1;
        f32x4_t acc[4][4];
        #pragma unroll
        for (int cf = 0; cf < 4; ++cf)
            #pragma unroll
            for (int pf = 0; pf < 4; ++pf)
                acc[cf][pf] = (f32x4_t){0.f, 0.f, 0.f, 0.f};

        #pragma unroll
        for (int kc = 0; kc < 2; ++kc) {
            const u16* wt = Wt1f + (((size_t)(kc*8 + cw*4)) << 9) + lane*8;
            bf16x8_t af[4];
            #pragma unroll
            for (int cf = 0; cf < 4; ++cf) af[cf] = *(const bf16x8_t*)(wt + (cf << 9));
            const int k0 = kc*32 + kg*8;
            #pragma unroll
            for (int pf = 0; pf < 4; ++pf) {
                bf16x8_t bfr = *(const bf16x8_t*)&lout[(pwv*64 + pf*16 + l15)*72 + k0];
                #pragma unroll
                for (int cf = 0; cf < 4; ++cf)
                    acc[cf][pf] = __builtin_amdgcn_mfma_f32_16x16x32_bf16(af[cf], bfr, acc[cf][pf], 0, 0, 0);
            }
        }

        #pragma unroll
        for (int cf = 0; cf < 4; ++cf) {
            float sarr[4], tarr[4];
            #pragma unroll
            for (int r = 0; r < 4; ++r) {
                int co = cw*64 + cf*16 + kg*4 + r;
                float s = e1g[co] * rsqrtf(e1v[co] + 1e-5f);
                sarr[r] = s; tarr[r] = e1b[co] - e1m[co]*s;
            }
            #pragma unroll
            for (int pf = 0; pf < 4; ++pf) {
                int px = pwv*64 + pf*16 + l15;
                size_t rowoff = (size_t)(orow0 + (px>>6))*64 + (px&63);
                #pragma unroll
                for (int r = 0; r < 4; ++r) {
                    int co = cw*64 + cf*16 + kg*4 + r;
                    float v = silu_f(acc[cf][pf][r]*sarr[r] + tarr[r]);
                    out[((size_t)(b*C_+co))*HW + rowoff] += c1*v;
                }
            }
        }
    }

    if (c2 != 0.f) {
        __syncthreads();   // order vs e1 phase (block-uniform guard)

        // ---- stage g1 ----
        for (int i = t; i < 64*25; i += 256) wl[(i/25)*26 + (i%25)] = e2bw[i];
        for (int i = t; i < 6*64*16; i += 256) {
            int q = i & 15, ch = (i >> 4) & 63, r = i >> 10;
            int hh = orow0 - 2 + r;
            u32 w0 = 0u, w1 = 0u;
            if (hh >= 0 && hh < H_) {
                const u32* src = (const u32*)(g1 + ((size_t)(b*CS+ch))*HW + hh*64 + q*4);
                w0 = src[0]; w1 = src[1];
            }
            u32* dst = (u32*)&lin[(r*64 + ch)*70 + 2 + q*4];
            dst[0] = w0; dst[1] = w1;
        }
        for (int i = t; i < 6*64; i += 256) {
            int ch = i & 63, r = i >> 6;
            *(u32*)&lin[(r*64 + ch)*70] = 0u;
            u32* e = (u32*)&lin[(r*64 + ch)*70 + 66];
            e[0] = 0u; e[1] = 0u;
        }
        __syncthreads();

        // out[:, :64] += c2*g1 for the 2 center rows (lin rows 2,3)
        for (int i = t; i < 2*64*16; i += 256) {
            int q = i & 15, ch = (i >> 4) & 63, r = i >> 10;
            const u16* src = &lin[((r+2)*64 + ch)*70 + 2 + q*4];
            float* op = out + ((size_t)(b*C_+ch))*HW + (size_t)(orow0+r)*64 + q*4;
            float4 ov = *(float4*)op;
            ov.x += c2*bf2f(src[0]); ov.y += c2*bf2f(src[1]);
            ov.z += c2*bf2f(src[2]); ov.w += c2*bf2f(src[3]);
            *(float4*)op = ov;
        }

        // ---- dw 5x5 + BN/SiLU -> out[:, 64:] += c2*g2 ----
        #pragma unroll
        for (int chi = 0; chi < 2; ++chi) {
            const int ch = chhalf*32 + chl + chi*16;
            const float* wch = &wl[ch*26];
            float accp[16];
            #pragma unroll
            for (int p = 0; p < 16; ++p) accp[p] = 0.f;
            #pragma unroll
            for (int kh = 0; kh < 5; ++kh) {
                const u16* src = &lin[((outrow + kh)*64 + ch)*70 + cs*16];
                float rb[20];
                #pragma unroll
                for (int k = 0; k < 10; ++k) {
                    u32 u = *(const u32*)(src + 2*k);
                    rb[2*k]   = __uint_as_float(u << 16);
                    rb[2*k+1] = __uint_as_float(u & 0xFFFF0000u);
                }
                #pragma unroll
                for (int kw = 0; kw < 5; ++kw) {
                    float wvv = wch[kh*5 + kw];
                    #pragma unroll
                    for (int p = 0; p < 16; ++p) accp[p] += rb[p+kw]*wvv;
                }
            }
            float s = e2bg[ch] * rsqrtf(e2bv[ch] + 1e-5f);
            float tt = e2bb[ch] - e2bm[ch]*s;
            float* op = out + ((size_t)(b*C_ + CS + ch))*HW + (size_t)(orow0+outrow)*64 + cs*16;
            #pragma unroll
            for (int q = 0; q < 4; ++q) {
                float4 ov = *(float4*)(op + q*4);
                ov.x += c2*silu_f(accp[q*4+0]*s + tt);
                ov.y += c2*silu_f(accp[q*4+1]*s + tt);
                ov.z += c2*silu_f(accp[q*4+2]*s + tt);
                ov.w += c2*silu_f(accp[q*4+3]*s + tt);
                *(float4*)(op + q*4) = ov;
            }
        }
    }
}

extern "C" void kernel_launch(void* const* d_in, const int* in_sizes, int n_in,
                              void* d_out, int out_size, void* d_ws, size_t ws_size,
                              hipStream_t stream) {
    const float* x    = (const float*)d_in[0];
    const float* wts  = (const float*)d_in[1];
    const int*   idxs = (const int*)  d_in[2];
    const float* e0w  = (const float*)d_in[3];
    const float* e0g  = (const float*)d_in[4];
    const float* e0b  = (const float*)d_in[5];
    const float* e0m  = (const float*)d_in[6];
    const float* e0v  = (const float*)d_in[7];
    const float* e1dw = (const float*)d_in[8];
    const float* e1pw = (const float*)d_in[9];
    const float* e1g  = (const float*)d_in[10];
    const float* e1b  = (const float*)d_in[11];
    const float* e1m  = (const float*)d_in[12];
    const float* e1v  = (const float*)d_in[13];
    const float* e2aw = (const float*)d_in[14];
    const float* e2ag = (const float*)d_in[15];
    const float* e2ab = (const float*)d_in[16];
    const float* e2am = (const float*)d_in[17];
    const float* e2av = (const float*)d_in[18];
    const float* e2bw = (const float*)d_in[19];
    const float* e2bg = (const float*)d_in[20];
    const float* e2bb = (const float*)d_in[21];
    const float* e2bm = (const float*)d_in[22];
    const float* e2bv = (const float*)d_in[23];

    float* out = (float*)d_out;

    u16* g1   = (u16*)d_ws;                      // 16.8 MB
    u16* Wt0f = g1 + (size_t)8388608;
    u16* Wt2f = Wt0f + 73728;
    u16* Wt1f = Wt2f + 73728;

    k_prep<<<128, 256, 0, stream>>>(e0w, e2aw, e1pw, Wt0f, Wt2f, Wt1f);
    k_conv<<<dim3(32, B_, 2), 256, 0, stream>>>(
        x, wts, idxs, Wt0f, Wt2f,
        e0g, e0b, e0m, e0v, e2ag, e2ab, e2am, e2av, out, g1);
    k_tail<<<dim3(32, B_), 256, 0, stream>>>(
        x, g1, wts, idxs, e1dw, Wt1f, e1g, e1b, e1m, e1v,
        e2bw, e2bg, e2bb, e2bm, e2bv, out);
}